// Round 15
// baseline (1641.242 us; speedup 1.0000x reference)
//
#include <hip/hip_runtime.h>
#include <hip/hip_bf16.h>
#include <math.h>

#define TT 2000
#define NN 256
#define DD 256
#define SS 45
#define SOUT 48
#define NTRANS_C 40
#define CHUNKS 40
#define CLEN 50   // TT / CHUNKS
#define BK 32     // x K-chunk (floats)
#define NCH (DD / BK)   // 8 chunks
#define XPAD 40   // bf16 x-tile row stride (ushorts)

// ---- MEASUREMENT ROUND (R15): inert reps to surface per-kernel counters ----
#define REP_KA 4    // extra inert K-loop passes in kA
#define REP_LD 4    // passes of the load-only probe
#define REP_KB 15   // extra inert scan passes in kB

typedef __attribute__((ext_vector_type(8))) short bf16x8;
typedef __attribute__((ext_vector_type(4))) float f32x4;

__device__ inline ushort f2bf_rne(float f) {
    unsigned u = __float_as_uint(f);
    unsigned r = u + 0x7fffu + ((u >> 16) & 1u);
    return (ushort)(r >> 16);
}
__device__ __forceinline__ int cvtpk(float lo, float hi) {
    int r;
    asm("v_cvt_pk_bf16_f32 %0, %1, %2" : "=v"(r) : "v"(lo), "v"(hi));
    return r;
}
__device__ __host__ __forceinline__ constexpr int sidx(int c) {
    return (c < 32) ? (4 * (c & 7) + (c >> 3))
         : (c < 36) ? (32 + 2 * (c - 32))
         : (c < 40) ? (32 + 2 * (c - 36) + 1)
         : c;
}
__device__ __forceinline__ int swz_idx(int s, int koff) {
    return s * DD + ((((koff >> 3) ^ (s & 7)) << 3) | (koff & 7));
}

// ---------------- Prep: W -> bf16 (RNE), pad to 48 rows; pad b ----------
__global__ __launch_bounds__(256) void kPrep(const float* __restrict__ W,
                                             const float* __restrict__ b,
                                             ushort* __restrict__ Whi,
                                             float* __restrict__ b48) {
    const int s = blockIdx.x;
    const int k = threadIdx.x;
    const float wv = (s < SS) ? W[s * DD + k] : 0.f;
    Whi[s * DD + k] = f2bf_rne(wv);
    if (k == 0) b48[s] = (s < SS) ? b[s] : 0.f;
}

// ---------------- Kernel A: R14 structure + REP_KA inert K-loop passes ----
__global__ __launch_bounds__(512, 6) void kA_mfma(const float* __restrict__ x,
                                                  const ushort* __restrict__ Whi,
                                                  const float* __restrict__ b48,
                                                  ushort* __restrict__ sc) {
    __shared__ ushort Wl[SOUT * DD];
    __shared__ ushort xw[8][16 * XPAD];
    const int tid = threadIdx.x;
    for (int idx = tid; idx < SOUT * (DD / 8); idx += 512) {
        const int s = idx >> 5;
        const int c8 = (idx & 31) * 8;
        const uint4 v = *reinterpret_cast<const uint4*>(Whi + s * DD + c8);
        *reinterpret_cast<uint4*>(&Wl[swz_idx(s, c8)]) = v;
    }
    __syncthreads();

    const int l = tid & 63, w = tid >> 6;
    const long m0 = (long)blockIdx.x * 128;
    const int r16 = l & 15;
    const int kg = l >> 4;
    const int lrow = l >> 3;
    const int lcol = (l & 7) * 4;
    const float* xp = x + (m0 + w * 16 + lrow) * DD + lcol;
    const float* xq = xp + 8 * DD;
    ushort* xs = xw[w];
    int2* xw0 = reinterpret_cast<int2*>(&xs[lrow * XPAD + lcol]);
    int2* xw1 = reinterpret_cast<int2*>(&xs[(lrow + 8) * XPAD + lcol]);
    const bf16x8* xrd = reinterpret_cast<const bf16x8*>(&xs[r16 * XPAD + kg * 8]);

    f32x4 acc[3] = {{0, 0, 0, 0}, {0, 0, 0, 0}, {0, 0, 0, 0}};

    float4 pf[2][2];
    pf[0][0] = *reinterpret_cast<const float4*>(xp + 0);
    pf[0][1] = *reinterpret_cast<const float4*>(xq + 0);
    pf[1][0] = *reinterpret_cast<const float4*>(xp + BK);
    pf[1][1] = *reinterpret_cast<const float4*>(xq + BK);

#pragma unroll
    for (int c = 0; c < NCH; ++c) {
        const float4 pa = pf[c & 1][0];
        const float4 qa = pf[c & 1][1];
        xw0->x = cvtpk(pa.x, pa.y);
        xw0->y = cvtpk(pa.z, pa.w);
        xw1->x = cvtpk(qa.x, qa.y);
        xw1->y = cvtpk(qa.z, qa.w);
        if (c + 2 < NCH) {
            pf[c & 1][0] = *reinterpret_cast<const float4*>(xp + (c + 2) * BK);
            pf[c & 1][1] = *reinterpret_cast<const float4*>(xq + (c + 2) * BK);
        }
        __builtin_amdgcn_sched_barrier(0);
        const bf16x8 a = *xrd;
        const int koff = c * BK + kg * 8;
        const bf16x8 b0 = *reinterpret_cast<const bf16x8*>(&Wl[swz_idx(0 * 16 + r16, koff)]);
        const bf16x8 b1 = *reinterpret_cast<const bf16x8*>(&Wl[swz_idx(1 * 16 + r16, koff)]);
        const bf16x8 b2 = *reinterpret_cast<const bf16x8*>(&Wl[swz_idx(2 * 16 + r16, koff)]);
        acc[0] = __builtin_amdgcn_mfma_f32_16x16x32_bf16(a, b0, acc[0], 0, 0, 0);
        acc[1] = __builtin_amdgcn_mfma_f32_16x16x32_bf16(a, b1, acc[1], 0, 0, 0);
        acc[2] = __builtin_amdgcn_mfma_f32_16x16x32_bf16(a, b2, acc[2], 0, 0, 0);
    }

    // ---- epilogue: LDS-staged coalesced score store (reuses Wl) ----
    __syncthreads();
    ushort* se = Wl;
#pragma unroll
    for (int jt = 0; jt < 3; ++jt) {
        const int col = jt * 16 + r16;
        const float bias = b48[col];
        int si;
        if (jt < 2) si = 4 * (col & 7) + (col >> 3);
        else if (r16 < 8) si = (r16 < 4) ? (32 + 2 * r16) : (32 + 2 * (r16 - 4) + 1);
        else si = 40 + (r16 - 8);
#pragma unroll
        for (int r = 0; r < 4; ++r) {
            const int lr = w * 16 + kg * 4 + r;
            const float y = acc[jt][r] + bias;
            float v;
            if (col < NTRANS_C) {
                const float e = __expf(2.f * y);
                v = 5.f * (1.f - 2.f / (e + 1.f));
            } else {
                v = y;
            }
            se[lr * SOUT + si] = f2bf_rne(v);
        }
    }
    __syncthreads();
    const uint4* su = reinterpret_cast<const uint4*>(se);
    uint4* du = reinterpret_cast<uint4*>(sc + m0 * SOUT);
    du[tid] = su[tid];
    if (tid < 256) du[512 + tid] = su[512 + tid];

    // ---- inert measurement passes (wave-private LDS, sunk output) ----
    f32x4 a2[3] = {{0, 0, 0, 0}, {0, 0, 0, 0}, {0, 0, 0, 0}};
#pragma unroll 1
    for (int rep = 0; rep < REP_KA; ++rep) {
        asm volatile("" ::: "memory");   // defeat cross-rep load CSE
        float4 pf2[2][2];
        pf2[0][0] = *reinterpret_cast<const float4*>(xp + 0);
        pf2[0][1] = *reinterpret_cast<const float4*>(xq + 0);
        pf2[1][0] = *reinterpret_cast<const float4*>(xp + BK);
        pf2[1][1] = *reinterpret_cast<const float4*>(xq + BK);
#pragma unroll
        for (int c = 0; c < NCH; ++c) {
            const float4 pa = pf2[c & 1][0];
            const float4 qa = pf2[c & 1][1];
            xw0->x = cvtpk(pa.x, pa.y);
            xw0->y = cvtpk(pa.z, pa.w);
            xw1->x = cvtpk(qa.x, qa.y);
            xw1->y = cvtpk(qa.z, qa.w);
            if (c + 2 < NCH) {
                pf2[c & 1][0] = *reinterpret_cast<const float4*>(xp + (c + 2) * BK);
                pf2[c & 1][1] = *reinterpret_cast<const float4*>(xq + (c + 2) * BK);
            }
            __builtin_amdgcn_sched_barrier(0);
            const bf16x8 a = *xrd;
            const int koff = c * BK + kg * 8;
            const bf16x8 b0 = *reinterpret_cast<const bf16x8*>(&Wl[swz_idx(0 * 16 + r16, koff)]);
            const bf16x8 b1 = *reinterpret_cast<const bf16x8*>(&Wl[swz_idx(1 * 16 + r16, koff)]);
            const bf16x8 b2 = *reinterpret_cast<const bf16x8*>(&Wl[swz_idx(2 * 16 + r16, koff)]);
            a2[0] = __builtin_amdgcn_mfma_f32_16x16x32_bf16(a, b0, a2[0], 0, 0, 0);
            a2[1] = __builtin_amdgcn_mfma_f32_16x16x32_bf16(a, b1, a2[1], 0, 0, 0);
            a2[2] = __builtin_amdgcn_mfma_f32_16x16x32_bf16(a, b2, a2[2], 0, 0, 0);
        }
    }
    asm volatile("" :: "v"(a2[0]), "v"(a2[1]), "v"(a2[2]));   // rule #17 sink
}

// ---------------- Probe: load-only x streaming, exact kA address stream ---
__global__ __launch_bounds__(512, 6) void kA_ldonly(const float* __restrict__ x) {
    const int tid = threadIdx.x;
    const int l = tid & 63, w = tid >> 6;
    const long m0 = (long)blockIdx.x * 128;
    const int lrow = l >> 3;
    const int lcol = (l & 7) * 4;
    const float* xp = x + (m0 + w * 16 + lrow) * DD + lcol;
    const float* xq = xp + 8 * DD;
    float4 s0 = {0, 0, 0, 0}, s1 = {0, 0, 0, 0};
#pragma unroll 1
    for (int rep = 0; rep < REP_LD; ++rep) {
        asm volatile("" ::: "memory");   // defeat cross-rep load CSE
#pragma unroll
        for (int c = 0; c < NCH; ++c) {
            const float4 a = *reinterpret_cast<const float4*>(xp + c * BK);
            const float4 b = *reinterpret_cast<const float4*>(xq + c * BK);
            s0.x += a.x; s0.y += a.y; s0.z += a.z; s0.w += a.w;
            s1.x += b.x; s1.y += b.y; s1.z += b.z; s1.w += b.w;
        }
    }
    asm volatile("" :: "v"(s0.x + s0.y + s0.z + s0.w + s1.x + s1.y + s1.z + s1.w));
}

// ---------------- DPP / swizzle cross-lane helpers -----------------------
#define DPP_XOR1 0xB1
#define DPP_XOR2 0x4E

__device__ inline float fmax_x1(float v) {
    const int d = __builtin_amdgcn_mov_dpp(__float_as_int(v), DPP_XOR1, 0xF, 0xF, true);
    return fmaxf(v, __int_as_float(d));
}
__device__ inline float fmax_x2(float v) {
    const int d = __builtin_amdgcn_mov_dpp(__float_as_int(v), DPP_XOR2, 0xF, 0xF, true);
    return fmaxf(v, __int_as_float(d));
}
__device__ inline float add_x1(float v) {
    const int d = __builtin_amdgcn_mov_dpp(__float_as_int(v), DPP_XOR1, 0xF, 0xF, true);
    return v + __int_as_float(d);
}
__device__ inline float add_x2(float v) {
    const int d = __builtin_amdgcn_mov_dpp(__float_as_int(v), DPP_XOR2, 0xF, 0xF, true);
    return v + __int_as_float(d);
}
__device__ inline float swz4(float v) {
    return __int_as_float(__builtin_amdgcn_ds_swizzle(__float_as_int(v), 0x101F));
}
__device__ inline float fmax_x4(float v) { return fmaxf(v, swz4(v)); }
__device__ inline float add_x4(float v) { return v + swz4(v); }
__device__ inline float sum8(float v) { return add_x4(add_x2(add_x1(v))); }
__device__ inline float max8(float v) { return fmax_x4(fmax_x2(fmax_x1(v))); }
__device__ inline float gat_k(float v) {
    return __int_as_float(__builtin_amdgcn_ds_swizzle(__float_as_int(v), 0x001B));
}

// ---------------- kB scan body (shared by real pass and inert reps) -------
__device__ __forceinline__ float kb_scan_once(const ushort* __restrict__ sc,
                                              int n, int c, int l) {
    const int col = l >> 3;
    const int j = l & 7;
    const int k = j & 3;
    float m = (j == col) ? 0.f : -60.f;
    const long stride = (long)NN * SOUT;
    const ushort* sp = sc + ((long)(c * CLEN) * NN + n) * SOUT;
    uint2 dv = *reinterpret_cast<const uint2*>(sp + 4 * j);
    unsigned dab = *reinterpret_cast<const unsigned*>(sp + 32 + 2 * k);
    for (int t = 0; t < CLEN; ++t) {
        const ushort* np = sp + stride;
        uint2 nv;
        unsigned nab;
        if (t + 1 < CLEN) {
            nv = *reinterpret_cast<const uint2*>(np + 4 * j);
            nab = *reinterpret_cast<const unsigned*>(np + 32 + 2 * k);
        }
        const float c0 = __uint_as_float(dv.x << 16);
        const float c1 = __uint_as_float(dv.x & 0xffff0000u);
        const float c2 = __uint_as_float(dv.y << 16);
        const float c3 = __uint_as_float(dv.y & 0xffff0000u);
        const float ca = __uint_as_float(dab << 16);
        const float cb = __uint_as_float(dab & 0xffff0000u);
        const float E0 = __expf(c0), E1 = __expf(c1), E2 = __expf(c2), E3 = __expf(c3);
        const float Ea = __expf(ca), Eb = __expf(cb);
        const float Mq = fmax_x2(fmax_x1(m));
        const float MqX = swz4(Mq);
        const float e = __expf(m - Mq);
        const float corr = __expf(MqX - Mq);
        const float p0l = add_x2(add_x1(e * E0));
        const float p1l = add_x2(add_x1(e * E1));
        const float p2l = add_x2(add_x1(e * E2));
        const float p3l = add_x2(add_x1(e * E3));
        const float p0 = fmaf(corr, swz4(p0l), p0l);
        const float p1 = fmaf(corr, swz4(p1l), p1l);
        const float p2 = fmaf(corr, swz4(p2l), p2l);
        const float p3 = fmaf(corr, swz4(p3l), p3l);
        const float Sb = fmaf(corr * gat_k(e), Ea, e * Eb);
        const float Slow = (j < 2) ? ((j == 0) ? p0 : p1)
                                   : ((j == 2) ? p2 : p3);
        const float S = (j < 4) ? Slow : Sb;
        m = Mq + __logf(S);
        dv = nv; dab = nab;
        sp = np;
    }
    return m;
}

// ---------------- Kernel B: real pass + REP_KB inert passes --------------
__global__ __launch_bounds__(64) void kB_scan(const ushort* __restrict__ sc,
                                              float* __restrict__ gbuf) {
    const int n = blockIdx.x;
    const int c = blockIdx.y;
    const int l = threadIdx.x;
    gbuf[((long)(n * CHUNKS + c)) * 64 + l] = kb_scan_once(sc, n, c, l);
    float macc = 0.f;
#pragma unroll 1
    for (int rep = 0; rep < REP_KB; ++rep) {
        asm volatile("" ::: "memory");
        macc += kb_scan_once(sc, n, c, l);
    }
    asm volatile("" :: "v"(macc));
}

// ---------------- butterfly lse helpers for kC ----------------
__device__ inline float lse8(float v) {
    const float m = max8(v);
    return m + __logf(sum8(__expf(v - m)));
}
__device__ inline float lse64(float v) {
    float m = v;
#pragma unroll
    for (int d = 1; d < 64; d <<= 1) m = fmaxf(m, __shfl_xor(m, d));
    float e = __expf(v - m);
#pragma unroll
    for (int d = 1; d < 64; d <<= 1) e += __shfl_xor(e, d);
    return m + __logf(e);
}

// ---------------- Kernel C: fold chunk matrices, emit logZ/T -------------
__global__ __launch_bounds__(64) void kC_combine(const float* __restrict__ gbuf,
                                                 float* __restrict__ logZT) {
    const int n = blockIdx.x;
    const int l = threadIdx.x;
    const int gi = (l & 7) * 8 + (l >> 3);
    float g[CHUNKS];
#pragma unroll
    for (int c = 0; c < CHUNKS; ++c)
        g[c] = gbuf[((long)(n * CHUNKS + c)) * 64 + gi];
    float u = -logf(8.f);
#pragma unroll
    for (int c = 0; c < CHUNKS; ++c) {
        const float nu = lse8(g[c] + u);
        u = __shfl(nu, ((l & 7) << 3) | (l >> 3));
    }
    const float z = lse64(u);
    if (l == 0) logZT[n] = z / (float)TT;
}

// ---------------- Kernel D: bf16 scores -> final f32 output --------------
__global__ __launch_bounds__(128) void kD_final(const ushort* __restrict__ sc,
                                                const float* __restrict__ logZT,
                                                float* __restrict__ out) {
    __shared__ float dout[128 * SOUT];
    const int tid = threadIdx.x;
    const long row0 = (long)blockIdx.x * 128;
    const long row = row0 + tid;
    const int n = (int)(row & (NN - 1));
    const float z = logZT[n];
    const ushort* srow = sc + row * SOUT;
    float st[48];
#pragma unroll
    for (int i = 0; i < 6; ++i) {
        const uint4 q = reinterpret_cast<const uint4*>(srow)[i];
        const unsigned wv[4] = {q.x, q.y, q.z, q.w};
#pragma unroll
        for (int t = 0; t < 4; ++t) {
            st[8 * i + 2 * t]     = __uint_as_float(wv[t] << 16);
            st[8 * i + 2 * t + 1] = __uint_as_float(wv[t] & 0xffff0000u);
        }
    }
    float* a = &dout[tid * SOUT];
#pragma unroll
    for (int c = 0; c < 40; ++c) a[c] = st[sidx(c)] - z;
    const float y40 = st[40], y41 = st[41], y42 = st[42], y43 = st[43], y44 = st[44];
    const float m3 = fmaxf(fmaxf(y40, y41), y42);
    const float l3 = m3 + __logf(__expf(y40 - m3) + __expf(y41 - m3) + __expf(y42 - m3));
    a[40] = y40 - l3; a[41] = y41 - l3; a[42] = y42 - l3;
    const float mA = fmaxf(y40, y43);
    const float lA = mA + __logf(__expf(y40 - mA) + __expf(y43 - mA));
    a[43] = y40 - lA; a[44] = y43 - lA;
    a[45] = 0.f;
    const float mB = fmaxf(y40, y44);
    const float lB = mB + __logf(__expf(y40 - mB) + __expf(y44 - mB));
    a[46] = y40 - lB; a[47] = y44 - lB;
    __syncthreads();
    const float4* sf = reinterpret_cast<const float4*>(dout);
    float4* df = reinterpret_cast<float4*>(out + row0 * SOUT);
#pragma unroll
    for (int kq = 0; kq < 12; ++kq)
        df[kq * 128 + tid] = sf[kq * 128 + tid];
}

extern "C" void kernel_launch(void* const* d_in, const int* in_sizes, int n_in,
                              void* d_out, int out_size, void* d_ws, size_t ws_size,
                              hipStream_t stream) {
    const float* x = (const float*)d_in[0];
    const float* W = (const float*)d_in[1];
    const float* b = (const float*)d_in[2];
    float* out = (float*)d_out;

    ushort* sc   = (ushort*)d_ws;                          // 49.15 MB
    float* gbuf  = (float*)((char*)d_ws + 49152000);       // 2.62 MB
    float* logZT = gbuf + (long)NN * CHUNKS * 64;          // 256 f32
    float* b48   = logZT + NN;                             // 48 f32
    ushort* Whi  = (ushort*)(b48 + SOUT);                  // 24 KB

    hipLaunchKernelGGL(kPrep, dim3(SOUT), dim3(DD), 0, stream, W, b, Whi, b48);
    hipLaunchKernelGGL(kA_mfma, dim3((TT * NN) / 128), dim3(512), 0, stream, x, Whi, b48, sc);
    hipLaunchKernelGGL(kA_ldonly, dim3((TT * NN) / 128), dim3(512), 0, stream, x);
    hipLaunchKernelGGL(kB_scan, dim3(NN, CHUNKS), dim3(64), 0, stream, sc, gbuf);
    hipLaunchKernelGGL(kC_combine, dim3(NN), dim3(64), 0, stream, gbuf, logZT);
    hipLaunchKernelGGL(kD_final, dim3((TT * NN) / 128), dim3(128), 0, stream, sc, logZT, out);
}

// Round 16
// 206.253 us; speedup vs baseline: 7.9574x; 7.9574x over previous
//
#include <hip/hip_runtime.h>
#include <hip/hip_bf16.h>
#include <math.h>

#define TT 2000
#define NN 256
#define DD 256
#define SS 45
#define SOUT 48
#define NTRANS_C 40
#define CHUNKS 40
#define CLEN 50   // TT / CHUNKS
#define BK 32     // x K-chunk (floats)
#define NCH (DD / BK)   // 8 chunks
#define XPAD 40   // bf16 x-tile row stride (ushorts)

typedef __attribute__((ext_vector_type(8))) short bf16x8;
typedef __attribute__((ext_vector_type(4))) float f32x4;

__device__ inline ushort f2bf_rne(float f) {
    unsigned u = __float_as_uint(f);
    unsigned r = u + 0x7fffu + ((u >> 16) & 1u);
    return (ushort)(r >> 16);
}
__device__ __forceinline__ int cvtpk(float lo, float hi) {
    int r;
    asm("v_cvt_pk_bf16_f32 %0, %1, %2" : "=v"(r) : "v"(lo), "v"(hi));
    return r;
}
__device__ __host__ __forceinline__ constexpr int sidx(int c) {
    return (c < 32) ? (4 * (c & 7) + (c >> 3))
         : (c < 36) ? (32 + 2 * (c - 32))
         : (c < 40) ? (32 + 2 * (c - 36) + 1)
         : c;
}
__device__ __forceinline__ int swz_idx(int s, int koff) {
    return s * DD + ((((koff >> 3) ^ (s & 7)) << 3) | (koff & 7));
}

// ---------------- Prep: W -> bf16 (RNE), pad to 48 rows; pad b ----------
__global__ __launch_bounds__(256) void kPrep(const float* __restrict__ W,
                                             const float* __restrict__ b,
                                             ushort* __restrict__ Whi,
                                             float* __restrict__ b48) {
    const int s = blockIdx.x;
    const int k = threadIdx.x;
    const float wv = (s < SS) ? W[s * DD + k] : 0.f;
    Whi[s * DD + k] = f2bf_rne(wv);
    if (k == 0) b48[s] = (s < SS) ? b[s] : 0.f;
}

// ---------------- Kernel A: exact R14 (224.9 us config) ------------------
__global__ __launch_bounds__(512, 6) void kA_mfma(const float* __restrict__ x,
                                                  const ushort* __restrict__ Whi,
                                                  const float* __restrict__ b48,
                                                  ushort* __restrict__ sc) {
    __shared__ ushort Wl[SOUT * DD];
    __shared__ ushort xw[8][16 * XPAD];
    const int tid = threadIdx.x;
    for (int idx = tid; idx < SOUT * (DD / 8); idx += 512) {
        const int s = idx >> 5;
        const int c8 = (idx & 31) * 8;
        const uint4 v = *reinterpret_cast<const uint4*>(Whi + s * DD + c8);
        *reinterpret_cast<uint4*>(&Wl[swz_idx(s, c8)]) = v;
    }
    __syncthreads();

    const int l = tid & 63, w = tid >> 6;
    const long m0 = (long)blockIdx.x * 128;
    const int r16 = l & 15;
    const int kg = l >> 4;
    const int lrow = l >> 3;
    const int lcol = (l & 7) * 4;
    const float* xp = x + (m0 + w * 16 + lrow) * DD + lcol;
    const float* xq = xp + 8 * DD;
    ushort* xs = xw[w];
    int2* xw0 = reinterpret_cast<int2*>(&xs[lrow * XPAD + lcol]);
    int2* xw1 = reinterpret_cast<int2*>(&xs[(lrow + 8) * XPAD + lcol]);
    const bf16x8* xrd = reinterpret_cast<const bf16x8*>(&xs[r16 * XPAD + kg * 8]);

    f32x4 acc[3] = {{0, 0, 0, 0}, {0, 0, 0, 0}, {0, 0, 0, 0}};

    float4 pf[2][2];
    pf[0][0] = *reinterpret_cast<const float4*>(xp + 0);
    pf[0][1] = *reinterpret_cast<const float4*>(xq + 0);
    pf[1][0] = *reinterpret_cast<const float4*>(xp + BK);
    pf[1][1] = *reinterpret_cast<const float4*>(xq + BK);

#pragma unroll
    for (int c = 0; c < NCH; ++c) {
        const float4 pa = pf[c & 1][0];
        const float4 qa = pf[c & 1][1];
        xw0->x = cvtpk(pa.x, pa.y);
        xw0->y = cvtpk(pa.z, pa.w);
        xw1->x = cvtpk(qa.x, qa.y);
        xw1->y = cvtpk(qa.z, qa.w);
        if (c + 2 < NCH) {
            pf[c & 1][0] = *reinterpret_cast<const float4*>(xp + (c + 2) * BK);
            pf[c & 1][1] = *reinterpret_cast<const float4*>(xq + (c + 2) * BK);
        }
        __builtin_amdgcn_sched_barrier(0);
        const bf16x8 a = *xrd;
        const int koff = c * BK + kg * 8;
        const bf16x8 b0 = *reinterpret_cast<const bf16x8*>(&Wl[swz_idx(0 * 16 + r16, koff)]);
        const bf16x8 b1 = *reinterpret_cast<const bf16x8*>(&Wl[swz_idx(1 * 16 + r16, koff)]);
        const bf16x8 b2 = *reinterpret_cast<const bf16x8*>(&Wl[swz_idx(2 * 16 + r16, koff)]);
        acc[0] = __builtin_amdgcn_mfma_f32_16x16x32_bf16(a, b0, acc[0], 0, 0, 0);
        acc[1] = __builtin_amdgcn_mfma_f32_16x16x32_bf16(a, b1, acc[1], 0, 0, 0);
        acc[2] = __builtin_amdgcn_mfma_f32_16x16x32_bf16(a, b2, acc[2], 0, 0, 0);
    }

    __syncthreads();
    ushort* se = Wl;
#pragma unroll
    for (int jt = 0; jt < 3; ++jt) {
        const int col = jt * 16 + r16;
        const float bias = b48[col];
        int si;
        if (jt < 2) si = 4 * (col & 7) + (col >> 3);
        else if (r16 < 8) si = (r16 < 4) ? (32 + 2 * r16) : (32 + 2 * (r16 - 4) + 1);
        else si = 40 + (r16 - 8);
#pragma unroll
        for (int r = 0; r < 4; ++r) {
            const int lr = w * 16 + kg * 4 + r;
            const float y = acc[jt][r] + bias;
            float v;
            if (col < NTRANS_C) {
                const float e = __expf(2.f * y);
                v = 5.f * (1.f - 2.f / (e + 1.f));
            } else {
                v = y;
            }
            se[lr * SOUT + si] = f2bf_rne(v);
        }
    }
    __syncthreads();
    const uint4* su = reinterpret_cast<const uint4*>(se);
    uint4* du = reinterpret_cast<uint4*>(sc + m0 * SOUT);
    du[tid] = su[tid];
    if (tid < 256) du[512 + tid] = su[512 + tid];
}

// ---------------- DPP / swizzle cross-lane helpers -----------------------
#define DPP_XOR1 0xB1
#define DPP_XOR2 0x4E

__device__ inline float fmax_x1(float v) {
    const int d = __builtin_amdgcn_mov_dpp(__float_as_int(v), DPP_XOR1, 0xF, 0xF, true);
    return fmaxf(v, __int_as_float(d));
}
__device__ inline float fmax_x2(float v) {
    const int d = __builtin_amdgcn_mov_dpp(__float_as_int(v), DPP_XOR2, 0xF, 0xF, true);
    return fmaxf(v, __int_as_float(d));
}
__device__ inline float add_x1(float v) {
    const int d = __builtin_amdgcn_mov_dpp(__float_as_int(v), DPP_XOR1, 0xF, 0xF, true);
    return v + __int_as_float(d);
}
__device__ inline float add_x2(float v) {
    const int d = __builtin_amdgcn_mov_dpp(__float_as_int(v), DPP_XOR2, 0xF, 0xF, true);
    return v + __int_as_float(d);
}
__device__ inline float swz4(float v) {   // lane ^ 4
    return __int_as_float(__builtin_amdgcn_ds_swizzle(__float_as_int(v), 0x101F));
}
__device__ inline float fmax_x4(float v) { return fmaxf(v, swz4(v)); }
__device__ inline float add_x4(float v) { return v + swz4(v); }
__device__ inline float sum8(float v) { return add_x4(add_x2(add_x1(v))); }
__device__ inline float max8(float v) { return fmax_x4(fmax_x2(fmax_x1(v))); }
__device__ inline float gat_k(float v) {
    return __int_as_float(__builtin_amdgcn_ds_swizzle(__float_as_int(v), 0x001B));
}
__device__ __forceinline__ float bperm(int byteaddr, float v) {
    return __int_as_float(__builtin_amdgcn_ds_bpermute(byteaddr, __float_as_int(v)));
}

// ---------------- Kernel B: linear-space scan, shared-exp ----------------
// R15 profile: VALU-issue-saturated (110%), 8 exp + 1 log per step with 8x
// redundant score-exps. Now: state P linear (no per-step max/exp/log);
// ONE exp per wave-step (lane i<40 owns score i, ds_bpermute distributes);
// exact power-of-2 rescale every 4 steps (integer ops); one log per chunk.
__global__ __launch_bounds__(64) void kB_scan(const ushort* __restrict__ sc,
                                              float* __restrict__ gbuf) {
    const int n = blockIdx.x;
    const int c = blockIdx.y;
    const int l = threadIdx.x;
    const int col = l >> 3;
    const int j = l & 7;
    const int k = j & 3;
    const int ls = (l < 40) ? sidx(l) : 0;   // lane -> score slot (shared-exp)
    // bpermute byte-addresses: E(s[r*8+j]) lives in lane r*8+j
    const int a0 = 4 * j, a1 = 4 * (8 + j), a2 = 4 * (16 + j), a3 = 4 * (24 + j);
    const int aa = 4 * (32 + k), ab = 4 * (36 + k);

    float P = (j == col) ? 1.f : 0.f;   // exact linear init
    int scale = 0;
    const long stride = (long)NN * SOUT;
    const ushort* sp = sc + ((long)(c * CLEN) * NN + n) * SOUT;

    // prep E for t=0
    float Eo = __expf(__uint_as_float(((unsigned)sp[ls]) << 16));
    float e0 = bperm(a0, Eo), e1 = bperm(a1, Eo), e2 = bperm(a2, Eo),
          e3 = bperm(a3, Eo), ea = bperm(aa, Eo), eb = bperm(ab, Eo);

    for (int t = 0; t < CLEN; ++t) {
        const ushort* np = sp + stride;
        const ushort nxt = (t + 1 < CLEN) ? np[ls] : (ushort)0;   // guarded
        // butterflied mat-vec in linear space
        float p0 = sum8(P * e0);
        float p1 = sum8(P * e1);
        float p2 = sum8(P * e2);
        float p3 = sum8(P * e3);
        const float pb = fmaf(gat_k(P), ea, P * eb);
        const float pl = (j < 2) ? ((j == 0) ? p0 : p1)
                                 : ((j == 2) ? p2 : p3);
        P = (j < 4) ? pl : pb;
        if ((t & 3) == 3) {   // exact pow2 rescale, integer-only
            const float Mx = max8(P);
            const int ex = ((__float_as_int(Mx) >> 23) & 255) - 127;
            P *= __int_as_float((unsigned)(127 - ex) << 23);
            scale += ex;
        }
        // prep E for t+1 (off the serial chain)
        Eo = __expf(__uint_as_float(((unsigned)nxt) << 16));
        e0 = bperm(a0, Eo); e1 = bperm(a1, Eo); e2 = bperm(a2, Eo);
        e3 = bperm(a3, Eo); ea = bperm(aa, Eo); eb = bperm(ab, Eo);
        sp = np;
    }
    const float m = __logf(P) + (float)scale * 0.6931471805599453f;
    gbuf[((long)(n * CHUNKS + c)) * 64 + l] = m;
}

// ---------------- butterfly lse helpers for kC ----------------
__device__ inline float lse8(float v) {
    const float m = max8(v);
    return m + __logf(sum8(__expf(v - m)));
}
__device__ inline float lse64(float v) {
    float m = v;
#pragma unroll
    for (int d = 1; d < 64; d <<= 1) m = fmaxf(m, __shfl_xor(m, d));
    float e = __expf(v - m);
#pragma unroll
    for (int d = 1; d < 64; d <<= 1) e += __shfl_xor(e, d);
    return m + __logf(e);
}

// ---------------- Kernel C: fold chunk matrices, emit logZ/T -------------
__global__ __launch_bounds__(64) void kC_combine(const float* __restrict__ gbuf,
                                                 float* __restrict__ logZT) {
    const int n = blockIdx.x;
    const int l = threadIdx.x;
    const int gi = (l & 7) * 8 + (l >> 3);
    float g[CHUNKS];
#pragma unroll
    for (int c = 0; c < CHUNKS; ++c)
        g[c] = gbuf[((long)(n * CHUNKS + c)) * 64 + gi];
    float u = -logf(8.f);
#pragma unroll
    for (int c = 0; c < CHUNKS; ++c) {
        const float nu = lse8(g[c] + u);
        u = __shfl(nu, ((l & 7) << 3) | (l >> 3));
    }
    const float z = lse64(u);
    if (l == 0) logZT[n] = z / (float)TT;
}

// ---------------- Kernel D: bf16 scores -> final f32 output --------------
__global__ __launch_bounds__(128) void kD_final(const ushort* __restrict__ sc,
                                                const float* __restrict__ logZT,
                                                float* __restrict__ out) {
    __shared__ float dout[128 * SOUT];
    const int tid = threadIdx.x;
    const long row0 = (long)blockIdx.x * 128;
    const long row = row0 + tid;
    const int n = (int)(row & (NN - 1));
    const float z = logZT[n];
    const ushort* srow = sc + row * SOUT;
    float st[48];
#pragma unroll
    for (int i = 0; i < 6; ++i) {
        const uint4 q = reinterpret_cast<const uint4*>(srow)[i];
        const unsigned wv[4] = {q.x, q.y, q.z, q.w};
#pragma unroll
        for (int t = 0; t < 4; ++t) {
            st[8 * i + 2 * t]     = __uint_as_float(wv[t] << 16);
            st[8 * i + 2 * t + 1] = __uint_as_float(wv[t] & 0xffff0000u);
        }
    }
    float* a = &dout[tid * SOUT];
#pragma unroll
    for (int c = 0; c < 40; ++c) a[c] = st[sidx(c)] - z;
    const float y40 = st[40], y41 = st[41], y42 = st[42], y43 = st[43], y44 = st[44];
    const float m3 = fmaxf(fmaxf(y40, y41), y42);
    const float l3 = m3 + __logf(__expf(y40 - m3) + __expf(y41 - m3) + __expf(y42 - m3));
    a[40] = y40 - l3; a[41] = y41 - l3; a[42] = y42 - l3;
    const float mA = fmaxf(y40, y43);
    const float lA = mA + __logf(__expf(y40 - mA) + __expf(y43 - mA));
    a[43] = y40 - lA; a[44] = y43 - lA;
    a[45] = 0.f;
    const float mB = fmaxf(y40, y44);
    const float lB = mB + __logf(__expf(y40 - mB) + __expf(y44 - mB));
    a[46] = y40 - lB; a[47] = y44 - lB;
    __syncthreads();
    const float4* sf = reinterpret_cast<const float4*>(dout);
    float4* df = reinterpret_cast<float4*>(out + row0 * SOUT);
#pragma unroll
    for (int kq = 0; kq < 12; ++kq)
        df[kq * 128 + tid] = sf[kq * 128 + tid];
}

extern "C" void kernel_launch(void* const* d_in, const int* in_sizes, int n_in,
                              void* d_out, int out_size, void* d_ws, size_t ws_size,
                              hipStream_t stream) {
    const float* x = (const float*)d_in[0];
    const float* W = (const float*)d_in[1];
    const float* b = (const float*)d_in[2];
    float* out = (float*)d_out;

    ushort* sc   = (ushort*)d_ws;                          // 49.15 MB
    float* gbuf  = (float*)((char*)d_ws + 49152000);       // 2.62 MB
    float* logZT = gbuf + (long)NN * CHUNKS * 64;          // 256 f32
    float* b48   = logZT + NN;                             // 48 f32
    ushort* Whi  = (ushort*)(b48 + SOUT);                  // 24 KB

    hipLaunchKernelGGL(kPrep, dim3(SOUT), dim3(DD), 0, stream, W, b, Whi, b48);
    hipLaunchKernelGGL(kA_mfma, dim3((TT * NN) / 128), dim3(512), 0, stream, x, Whi, b48, sc);
    hipLaunchKernelGGL(kB_scan, dim3(NN, CHUNKS), dim3(64), 0, stream, sc, gbuf);
    hipLaunchKernelGGL(kC_combine, dim3(NN), dim3(64), 0, stream, gbuf, logZT);
    hipLaunchKernelGGL(kD_final, dim3((TT * NN) / 128), dim3(128), 0, stream, sc, logZT, out);
}

// Round 17
// 195.698 us; speedup vs baseline: 8.3866x; 1.0539x over previous
//
#include <hip/hip_runtime.h>
#include <hip/hip_bf16.h>
#include <math.h>

#define TT 2000
#define NN 256
#define DD 256
#define SS 45
#define SOUT 48
#define NTRANS_C 40
#define CHUNKS 40
#define CLEN 50   // TT / CHUNKS
#define BK 32     // x K-chunk (floats)
#define NCH (DD / BK)   // 8 chunks
#define XPAD 40   // bf16 x-tile row stride (ushorts)

typedef __attribute__((ext_vector_type(8))) short bf16x8;
typedef __attribute__((ext_vector_type(4))) float f32x4;

__device__ inline ushort f2bf_rne(float f) {
    unsigned u = __float_as_uint(f);
    unsigned r = u + 0x7fffu + ((u >> 16) & 1u);
    return (ushort)(r >> 16);
}
__device__ __forceinline__ int cvtpk(float lo, float hi) {
    int r;
    asm("v_cvt_pk_bf16_f32 %0, %1, %2" : "=v"(r) : "v"(lo), "v"(hi));
    return r;
}
__device__ __host__ __forceinline__ constexpr int sidx(int c) {
    return (c < 32) ? (4 * (c & 7) + (c >> 3))
         : (c < 36) ? (32 + 2 * (c - 32))
         : (c < 40) ? (32 + 2 * (c - 36) + 1)
         : c;
}
__device__ __forceinline__ int swz_idx(int s, int koff) {
    return s * DD + ((((koff >> 3) ^ (s & 7)) << 3) | (koff & 7));
}

// ---------------- Prep: W -> bf16 (RNE), pad to 48 rows; pad b ----------
__global__ __launch_bounds__(256) void kPrep(const float* __restrict__ W,
                                             const float* __restrict__ b,
                                             ushort* __restrict__ Whi,
                                             float* __restrict__ b48) {
    const int s = blockIdx.x;
    const int k = threadIdx.x;
    const float wv = (s < SS) ? W[s * DD + k] : 0.f;
    Whi[s * DD + k] = f2bf_rne(wv);
    if (k == 0) b48[s] = (s < SS) ? b[s] : 0.f;
}

// ---------------- Kernel A: exact R14/R16 config --------------------------
__global__ __launch_bounds__(512, 6) void kA_mfma(const float* __restrict__ x,
                                                  const ushort* __restrict__ Whi,
                                                  const float* __restrict__ b48,
                                                  ushort* __restrict__ sc) {
    __shared__ ushort Wl[SOUT * DD];
    __shared__ ushort xw[8][16 * XPAD];
    const int tid = threadIdx.x;
    for (int idx = tid; idx < SOUT * (DD / 8); idx += 512) {
        const int s = idx >> 5;
        const int c8 = (idx & 31) * 8;
        const uint4 v = *reinterpret_cast<const uint4*>(Whi + s * DD + c8);
        *reinterpret_cast<uint4*>(&Wl[swz_idx(s, c8)]) = v;
    }
    __syncthreads();

    const int l = tid & 63, w = tid >> 6;
    const long m0 = (long)blockIdx.x * 128;
    const int r16 = l & 15;
    const int kg = l >> 4;
    const int lrow = l >> 3;
    const int lcol = (l & 7) * 4;
    const float* xp = x + (m0 + w * 16 + lrow) * DD + lcol;
    const float* xq = xp + 8 * DD;
    ushort* xs = xw[w];
    int2* xw0 = reinterpret_cast<int2*>(&xs[lrow * XPAD + lcol]);
    int2* xw1 = reinterpret_cast<int2*>(&xs[(lrow + 8) * XPAD + lcol]);
    const bf16x8* xrd = reinterpret_cast<const bf16x8*>(&xs[r16 * XPAD + kg * 8]);

    f32x4 acc[3] = {{0, 0, 0, 0}, {0, 0, 0, 0}, {0, 0, 0, 0}};

    float4 pf[2][2];
    pf[0][0] = *reinterpret_cast<const float4*>(xp + 0);
    pf[0][1] = *reinterpret_cast<const float4*>(xq + 0);
    pf[1][0] = *reinterpret_cast<const float4*>(xp + BK);
    pf[1][1] = *reinterpret_cast<const float4*>(xq + BK);

#pragma unroll
    for (int c = 0; c < NCH; ++c) {
        const float4 pa = pf[c & 1][0];
        const float4 qa = pf[c & 1][1];
        xw0->x = cvtpk(pa.x, pa.y);
        xw0->y = cvtpk(pa.z, pa.w);
        xw1->x = cvtpk(qa.x, qa.y);
        xw1->y = cvtpk(qa.z, qa.w);
        if (c + 2 < NCH) {
            pf[c & 1][0] = *reinterpret_cast<const float4*>(xp + (c + 2) * BK);
            pf[c & 1][1] = *reinterpret_cast<const float4*>(xq + (c + 2) * BK);
        }
        __builtin_amdgcn_sched_barrier(0);
        const bf16x8 a = *xrd;
        const int koff = c * BK + kg * 8;
        const bf16x8 b0 = *reinterpret_cast<const bf16x8*>(&Wl[swz_idx(0 * 16 + r16, koff)]);
        const bf16x8 b1 = *reinterpret_cast<const bf16x8*>(&Wl[swz_idx(1 * 16 + r16, koff)]);
        const bf16x8 b2 = *reinterpret_cast<const bf16x8*>(&Wl[swz_idx(2 * 16 + r16, koff)]);
        acc[0] = __builtin_amdgcn_mfma_f32_16x16x32_bf16(a, b0, acc[0], 0, 0, 0);
        acc[1] = __builtin_amdgcn_mfma_f32_16x16x32_bf16(a, b1, acc[1], 0, 0, 0);
        acc[2] = __builtin_amdgcn_mfma_f32_16x16x32_bf16(a, b2, acc[2], 0, 0, 0);
    }

    __syncthreads();
    ushort* se = Wl;
#pragma unroll
    for (int jt = 0; jt < 3; ++jt) {
        const int col = jt * 16 + r16;
        const float bias = b48[col];
        int si;
        if (jt < 2) si = 4 * (col & 7) + (col >> 3);
        else if (r16 < 8) si = (r16 < 4) ? (32 + 2 * r16) : (32 + 2 * (r16 - 4) + 1);
        else si = 40 + (r16 - 8);
#pragma unroll
        for (int r = 0; r < 4; ++r) {
            const int lr = w * 16 + kg * 4 + r;
            const float y = acc[jt][r] + bias;
            float v;
            if (col < NTRANS_C) {
                const float e = __expf(2.f * y);
                v = 5.f * (1.f - 2.f / (e + 1.f));
            } else {
                v = y;
            }
            se[lr * SOUT + si] = f2bf_rne(v);
        }
    }
    __syncthreads();
    const uint4* su = reinterpret_cast<const uint4*>(se);
    uint4* du = reinterpret_cast<uint4*>(sc + m0 * SOUT);
    du[tid] = su[tid];
    if (tid < 256) du[512 + tid] = su[512 + tid];
}

// ---------------- DPP / swizzle cross-lane helpers -----------------------
#define DPP_XOR1 0xB1
#define DPP_XOR2 0x4E

__device__ inline float fmax_x1(float v) {
    const int d = __builtin_amdgcn_mov_dpp(__float_as_int(v), DPP_XOR1, 0xF, 0xF, true);
    return fmaxf(v, __int_as_float(d));
}
__device__ inline float fmax_x2(float v) {
    const int d = __builtin_amdgcn_mov_dpp(__float_as_int(v), DPP_XOR2, 0xF, 0xF, true);
    return fmaxf(v, __int_as_float(d));
}
__device__ inline float add_x1(float v) {
    const int d = __builtin_amdgcn_mov_dpp(__float_as_int(v), DPP_XOR1, 0xF, 0xF, true);
    return v + __int_as_float(d);
}
__device__ inline float add_x2(float v) {
    const int d = __builtin_amdgcn_mov_dpp(__float_as_int(v), DPP_XOR2, 0xF, 0xF, true);
    return v + __int_as_float(d);
}
__device__ inline float swz4(float v) {   // lane ^ 4
    return __int_as_float(__builtin_amdgcn_ds_swizzle(__float_as_int(v), 0x101F));
}
__device__ inline float fmax_x4(float v) { return fmaxf(v, swz4(v)); }
__device__ inline float add_x4(float v) { return v + swz4(v); }
__device__ inline float sum8(float v) { return add_x4(add_x2(add_x1(v))); }
__device__ inline float max8(float v) { return fmax_x4(fmax_x2(fmax_x1(v))); }

// ---------------- Kernel B: pair-layout linear scan ----------------------
// R16 analysis: kB was LDS-pipe-contention-bound (11 DS ops/chunk-step).
// Now: quad=column, lane holds states d and 4+d (Plo/Phi); wave handles 2
// chunks (halves). 8-sum -> 2 quad-DPP butterflies (VALU); base2 row is
// lane-local. E distributed through a 768B double-buffered LDS tile whose
// sidx-permuted slots make each lane's 10 E-values 3 contiguous vectors:
// per wave-step DS = 2 write + 3 read (was 22 for 2 chunks).
__global__ __launch_bounds__(64) void kB_scan(const ushort* __restrict__ sc,
                                              float* __restrict__ gbuf) {
    __shared__ float el[2][2][48];   // [half][buf][slot]
    const int n = blockIdx.x;
    const int l = threadIdx.x;
    const int h = l >> 5;            // half -> chunk
    const int l32 = l & 31;
    const int d = l32 & 3;           // state index within quad
    const int q = l32 >> 2;          // column 0..7
    const int ch = blockIdx.y * 2 + h;
    const long stride = (long)NN * SOUT;
    const ushort* sp = sc + ((long)(ch * CLEN) * NN + n) * SOUT;

    float Plo = (d == q) ? 1.f : 0.f;        // M[d][col]
    float Phi = (4 + d == q) ? 1.f : 0.f;    // M[4+d][col]
    int scale = 0;
    float* eh = &el[h][0][0];

    // stage E for t=0 (wave-private: no barriers anywhere)
    {
        const float s1 = __uint_as_float(((unsigned)sp[l32]) << 16);
        eh[l32] = __expf(s1);
        if (l32 < 8) {
            const float s2 = __uint_as_float(((unsigned)sp[32 + l32]) << 16);
            eh[32 + l32] = __expf(s2);
        }
    }

    for (int t = 0; t < CLEN; ++t) {
        const float* er = eh + (t & 1) * 48;
        const float4 Elo = *reinterpret_cast<const float4*>(er + 4 * d);
        const float4 Ehi = *reinterpret_cast<const float4*>(er + 16 + 4 * d);
        const float2 Eab = *reinterpret_cast<const float2*>(er + 32 + 2 * d);
        if (t + 1 < CLEN) {   // guarded prefetch+stage of E[t+1]
            const ushort* np = sp + stride;
            float* ew = eh + ((t + 1) & 1) * 48;
            const float s1 = __uint_as_float(((unsigned)np[l32]) << 16);
            ew[l32] = __expf(s1);
            if (l32 < 8) {
                const float s2 = __uint_as_float(((unsigned)np[32 + l32]) << 16);
                ew[32 + l32] = __expf(s2);
            }
            sp = np;
        }
        // linear-space step
        float v0 = fmaf(Plo, Elo.x, Phi * Ehi.x);
        float v1 = fmaf(Plo, Elo.y, Phi * Ehi.y);
        float v2 = fmaf(Plo, Elo.z, Phi * Ehi.z);
        float v3 = fmaf(Plo, Elo.w, Phi * Ehi.w);
        v0 = add_x2(add_x1(v0));   // quad-sum (VALU DPP only)
        v1 = add_x2(add_x1(v1));
        v2 = add_x2(add_x1(v2));
        v3 = add_x2(add_x1(v3));
        const float PhiN = fmaf(Plo, Eab.x, Phi * Eab.y);   // lane-local base2
        const float pa_ = (d & 1) ? v1 : v0;
        const float pb_ = (d & 1) ? v3 : v2;
        Plo = (d & 2) ? pb_ : pa_;
        Phi = PhiN;
        if ((t & 3) == 3) {   // exact pow2 rescale, per-quad
            const float Mx = fmax_x2(fmax_x1(fmaxf(Plo, Phi)));
            const int ex = ((__float_as_int(Mx) >> 23) & 255) - 127;
            const float s = __int_as_float((unsigned)(127 - ex) << 23);
            Plo *= s;
            Phi *= s;
            scale += ex;
        }
    }
    const float base = (float)scale * 0.6931471805599453f;
    float* gb = gbuf + ((long)(n * CHUNKS + ch)) * 64;
    gb[q * 8 + d] = __logf(Plo) + base;       // G[d][col]
    gb[q * 8 + 4 + d] = __logf(Phi) + base;   // G[4+d][col]
}

// ---------------- butterfly lse helpers for kC ----------------
__device__ inline float lse8(float v) {
    const float m = max8(v);
    return m + __logf(sum8(__expf(v - m)));
}
__device__ inline float lse64(float v) {
    float m = v;
#pragma unroll
    for (int d = 1; d < 64; d <<= 1) m = fmaxf(m, __shfl_xor(m, d));
    float e = __expf(v - m);
#pragma unroll
    for (int d = 1; d < 64; d <<= 1) e += __shfl_xor(e, d);
    return m + __logf(e);
}

// ---------------- Kernel C: fold chunk matrices, emit logZ/T -------------
__global__ __launch_bounds__(64) void kC_combine(const float* __restrict__ gbuf,
                                                 float* __restrict__ logZT) {
    const int n = blockIdx.x;
    const int l = threadIdx.x;
    const int gi = (l & 7) * 8 + (l >> 3);
    float g[CHUNKS];
#pragma unroll
    for (int c = 0; c < CHUNKS; ++c)
        g[c] = gbuf[((long)(n * CHUNKS + c)) * 64 + gi];
    float u = -logf(8.f);
#pragma unroll
    for (int c = 0; c < CHUNKS; ++c) {
        const float nu = lse8(g[c] + u);
        u = __shfl(nu, ((l & 7) << 3) | (l >> 3));
    }
    const float z = lse64(u);
    if (l == 0) logZT[n] = z / (float)TT;
}

// ---------------- Kernel D: bf16 scores -> final f32 output --------------
__global__ __launch_bounds__(128) void kD_final(const ushort* __restrict__ sc,
                                                const float* __restrict__ logZT,
                                                float* __restrict__ out) {
    __shared__ float dout[128 * SOUT];
    const int tid = threadIdx.x;
    const long row0 = (long)blockIdx.x * 128;
    const long row = row0 + tid;
    const int n = (int)(row & (NN - 1));
    const float z = logZT[n];
    const ushort* srow = sc + row * SOUT;
    float st[48];
#pragma unroll
    for (int i = 0; i < 6; ++i) {
        const uint4 qv = reinterpret_cast<const uint4*>(srow)[i];
        const unsigned wv[4] = {qv.x, qv.y, qv.z, qv.w};
#pragma unroll
        for (int t = 0; t < 4; ++t) {
            st[8 * i + 2 * t]     = __uint_as_float(wv[t] << 16);
            st[8 * i + 2 * t + 1] = __uint_as_float(wv[t] & 0xffff0000u);
        }
    }
    float* a = &dout[tid * SOUT];
#pragma unroll
    for (int c = 0; c < 40; ++c) a[c] = st[sidx(c)] - z;
    const float y40 = st[40], y41 = st[41], y42 = st[42], y43 = st[43], y44 = st[44];
    const float m3 = fmaxf(fmaxf(y40, y41), y42);
    const float l3 = m3 + __logf(__expf(y40 - m3) + __expf(y41 - m3) + __expf(y42 - m3));
    a[40] = y40 - l3; a[41] = y41 - l3; a[42] = y42 - l3;
    const float mA = fmaxf(y40, y43);
    const float lA = mA + __logf(__expf(y40 - mA) + __expf(y43 - mA));
    a[43] = y40 - lA; a[44] = y43 - lA;
    a[45] = 0.f;
    const float mB = fmaxf(y40, y44);
    const float lB = mB + __logf(__expf(y40 - mB) + __expf(y44 - mB));
    a[46] = y40 - lB; a[47] = y44 - lB;
    __syncthreads();
    const float4* sf = reinterpret_cast<const float4*>(dout);
    float4* df = reinterpret_cast<float4*>(out + row0 * SOUT);
#pragma unroll
    for (int kq = 0; kq < 12; ++kq)
        df[kq * 128 + tid] = sf[kq * 128 + tid];
}

extern "C" void kernel_launch(void* const* d_in, const int* in_sizes, int n_in,
                              void* d_out, int out_size, void* d_ws, size_t ws_size,
                              hipStream_t stream) {
    const float* x = (const float*)d_in[0];
    const float* W = (const float*)d_in[1];
    const float* b = (const float*)d_in[2];
    float* out = (float*)d_out;

    ushort* sc   = (ushort*)d_ws;                          // 49.15 MB
    float* gbuf  = (float*)((char*)d_ws + 49152000);       // 2.62 MB
    float* logZT = gbuf + (long)NN * CHUNKS * 64;          // 256 f32
    float* b48   = logZT + NN;                             // 48 f32
    ushort* Whi  = (ushort*)(b48 + SOUT);                  // 24 KB

    hipLaunchKernelGGL(kPrep, dim3(SOUT), dim3(DD), 0, stream, W, b, Whi, b48);
    hipLaunchKernelGGL(kA_mfma, dim3((TT * NN) / 128), dim3(512), 0, stream, x, Whi, b48, sc);
    hipLaunchKernelGGL(kB_scan, dim3(NN, CHUNKS / 2), dim3(64), 0, stream, sc, gbuf);
    hipLaunchKernelGGL(kC_combine, dim3(NN), dim3(64), 0, stream, gbuf, logZT);
    hipLaunchKernelGGL(kD_final, dim3((TT * NN) / 128), dim3(128), 0, stream, sc, logZT, out);
}

// Round 18
// 186.426 us; speedup vs baseline: 8.8037x; 1.0497x over previous
//
#include <hip/hip_runtime.h>
#include <hip/hip_bf16.h>
#include <math.h>

#define TT 2000
#define NN 256
#define DD 256
#define SS 45
#define SOUT 48
#define NTRANS_C 40
#define CHUNKS 40
#define CLEN 50   // TT / CHUNKS
#define BK 32     // x K-chunk (floats)
#define NCH (DD / BK)   // 8 chunks
#define XPAD 40   // bf16 x-tile row stride (ushorts)

typedef __attribute__((ext_vector_type(8))) short bf16x8;
typedef __attribute__((ext_vector_type(4))) float f32x4;

__device__ inline ushort f2bf_rne(float f) {
    unsigned u = __float_as_uint(f);
    unsigned r = u + 0x7fffu + ((u >> 16) & 1u);
    return (ushort)(r >> 16);
}
__device__ __forceinline__ int cvtpk(float lo, float hi) {
    int r;
    asm("v_cvt_pk_bf16_f32 %0, %1, %2" : "=v"(r) : "v"(lo), "v"(hi));
    return r;
}
__device__ __forceinline__ float bf2f(ushort h) {
    return __uint_as_float(((unsigned)h) << 16);
}
__device__ __host__ __forceinline__ constexpr int sidx(int c) {
    return (c < 32) ? (4 * (c & 7) + (c >> 3))
         : (c < 36) ? (32 + 2 * (c - 32))
         : (c < 40) ? (32 + 2 * (c - 36) + 1)
         : c;
}
__device__ __forceinline__ int swz_idx(int s, int koff) {
    return s * DD + ((((koff >> 3) ^ (s & 7)) << 3) | (koff & 7));
}

// ---------------- Prep: W -> bf16 (RNE), pad to 48 rows; pad b ----------
__global__ __launch_bounds__(256) void kPrep(const float* __restrict__ W,
                                             const float* __restrict__ b,
                                             ushort* __restrict__ Whi,
                                             float* __restrict__ b48) {
    const int s = blockIdx.x;
    const int k = threadIdx.x;
    const float wv = (s < SS) ? W[s * DD + k] : 0.f;
    Whi[s * DD + k] = f2bf_rne(wv);
    if (k == 0) b48[s] = (s < SS) ? b[s] : 0.f;
}

// ---------------- Kernel A: exact R14/R17 config --------------------------
__global__ __launch_bounds__(512, 6) void kA_mfma(const float* __restrict__ x,
                                                  const ushort* __restrict__ Whi,
                                                  const float* __restrict__ b48,
                                                  ushort* __restrict__ sc) {
    __shared__ ushort Wl[SOUT * DD];
    __shared__ ushort xw[8][16 * XPAD];
    const int tid = threadIdx.x;
    for (int idx = tid; idx < SOUT * (DD / 8); idx += 512) {
        const int s = idx >> 5;
        const int c8 = (idx & 31) * 8;
        const uint4 v = *reinterpret_cast<const uint4*>(Whi + s * DD + c8);
        *reinterpret_cast<uint4*>(&Wl[swz_idx(s, c8)]) = v;
    }
    __syncthreads();

    const int l = tid & 63, w = tid >> 6;
    const long m0 = (long)blockIdx.x * 128;
    const int r16 = l & 15;
    const int kg = l >> 4;
    const int lrow = l >> 3;
    const int lcol = (l & 7) * 4;
    const float* xp = x + (m0 + w * 16 + lrow) * DD + lcol;
    const float* xq = xp + 8 * DD;
    ushort* xs = xw[w];
    int2* xw0 = reinterpret_cast<int2*>(&xs[lrow * XPAD + lcol]);
    int2* xw1 = reinterpret_cast<int2*>(&xs[(lrow + 8) * XPAD + lcol]);
    const bf16x8* xrd = reinterpret_cast<const bf16x8*>(&xs[r16 * XPAD + kg * 8]);

    f32x4 acc[3] = {{0, 0, 0, 0}, {0, 0, 0, 0}, {0, 0, 0, 0}};

    float4 pf[2][2];
    pf[0][0] = *reinterpret_cast<const float4*>(xp + 0);
    pf[0][1] = *reinterpret_cast<const float4*>(xq + 0);
    pf[1][0] = *reinterpret_cast<const float4*>(xp + BK);
    pf[1][1] = *reinterpret_cast<const float4*>(xq + BK);

#pragma unroll
    for (int c = 0; c < NCH; ++c) {
        const float4 pa = pf[c & 1][0];
        const float4 qa = pf[c & 1][1];
        xw0->x = cvtpk(pa.x, pa.y);
        xw0->y = cvtpk(pa.z, pa.w);
        xw1->x = cvtpk(qa.x, qa.y);
        xw1->y = cvtpk(qa.z, qa.w);
        if (c + 2 < NCH) {
            pf[c & 1][0] = *reinterpret_cast<const float4*>(xp + (c + 2) * BK);
            pf[c & 1][1] = *reinterpret_cast<const float4*>(xq + (c + 2) * BK);
        }
        __builtin_amdgcn_sched_barrier(0);
        const bf16x8 a = *xrd;
        const int koff = c * BK + kg * 8;
        const bf16x8 b0 = *reinterpret_cast<const bf16x8*>(&Wl[swz_idx(0 * 16 + r16, koff)]);
        const bf16x8 b1 = *reinterpret_cast<const bf16x8*>(&Wl[swz_idx(1 * 16 + r16, koff)]);
        const bf16x8 b2 = *reinterpret_cast<const bf16x8*>(&Wl[swz_idx(2 * 16 + r16, koff)]);
        acc[0] = __builtin_amdgcn_mfma_f32_16x16x32_bf16(a, b0, acc[0], 0, 0, 0);
        acc[1] = __builtin_amdgcn_mfma_f32_16x16x32_bf16(a, b1, acc[1], 0, 0, 0);
        acc[2] = __builtin_amdgcn_mfma_f32_16x16x32_bf16(a, b2, acc[2], 0, 0, 0);
    }

    __syncthreads();
    ushort* se = Wl;
#pragma unroll
    for (int jt = 0; jt < 3; ++jt) {
        const int col = jt * 16 + r16;
        const float bias = b48[col];
        int si;
        if (jt < 2) si = 4 * (col & 7) + (col >> 3);
        else if (r16 < 8) si = (r16 < 4) ? (32 + 2 * r16) : (32 + 2 * (r16 - 4) + 1);
        else si = 40 + (r16 - 8);
#pragma unroll
        for (int r = 0; r < 4; ++r) {
            const int lr = w * 16 + kg * 4 + r;
            const float y = acc[jt][r] + bias;
            float v;
            if (col < NTRANS_C) {
                const float e = __expf(2.f * y);
                v = 5.f * (1.f - 2.f / (e + 1.f));
            } else {
                v = y;
            }
            se[lr * SOUT + si] = f2bf_rne(v);
        }
    }
    __syncthreads();
    const uint4* su = reinterpret_cast<const uint4*>(se);
    uint4* du = reinterpret_cast<uint4*>(sc + m0 * SOUT);
    du[tid] = su[tid];
    if (tid < 256) du[512 + tid] = su[512 + tid];
}

// ---------------- DPP / swizzle cross-lane helpers -----------------------
#define DPP_XOR1 0xB1
#define DPP_XOR2 0x4E

__device__ inline float fmax_x1(float v) {
    const int d = __builtin_amdgcn_mov_dpp(__float_as_int(v), DPP_XOR1, 0xF, 0xF, true);
    return fmaxf(v, __int_as_float(d));
}
__device__ inline float fmax_x2(float v) {
    const int d = __builtin_amdgcn_mov_dpp(__float_as_int(v), DPP_XOR2, 0xF, 0xF, true);
    return fmaxf(v, __int_as_float(d));
}
__device__ inline float add_x1(float v) {
    const int d = __builtin_amdgcn_mov_dpp(__float_as_int(v), DPP_XOR1, 0xF, 0xF, true);
    return v + __int_as_float(d);
}
__device__ inline float add_x2(float v) {
    const int d = __builtin_amdgcn_mov_dpp(__float_as_int(v), DPP_XOR2, 0xF, 0xF, true);
    return v + __int_as_float(d);
}
__device__ inline float swz4(float v) {   // lane ^ 4
    return __int_as_float(__builtin_amdgcn_ds_swizzle(__float_as_int(v), 0x101F));
}
__device__ inline float fmax_x4(float v) { return fmaxf(v, swz4(v)); }
__device__ inline float add_x4(float v) { return v + swz4(v); }
__device__ inline float sum8(float v) { return add_x4(add_x2(add_x1(v))); }
__device__ inline float max8(float v) { return fmax_x4(fmax_x2(fmax_x1(v))); }

// ---------------- Kernel B: pair-layout linear scan, 2 steps / iter ------
// R17 residual = DS-op count (5/step). Parity-interleaved E-tile
// elp[half][u-par][slot][t-par]: writes pack 2 steps into b64 (1/step avg),
// reads deliver both parities per float4 (5 reads / 2 steps). DS 10->7 per
// 2 steps; half the loop iterations. Math identical to R17.
__global__ __launch_bounds__(64) void kB_scan(const ushort* __restrict__ sc,
                                              float* __restrict__ gbuf) {
    __shared__ float elp[2][2][48][2];   // 6 KB: [half][u-par][slot][t-par]
    const int n = blockIdx.x;
    const int l = threadIdx.x;
    const int h = l >> 5;            // half -> chunk
    const int l32 = l & 31;
    const int d = l32 & 3;           // state index within quad
    const int q = l32 >> 2;          // column 0..7
    const int ch = blockIdx.y * 2 + h;
    const long stride = (long)NN * SOUT;
    const ushort* sp = sc + ((long)(ch * CLEN) * NN + n) * SOUT;   // row t=0

    float Plo = (d == q) ? 1.f : 0.f;        // M[d][col]
    float Phi = (4 + d == q) ? 1.f : 0.f;    // M[4+d][col]
    int scale = 0;

    // stage E for t=0,1 into u-parity buffer 0 (wave-private, no barriers)
    {
        float2 e2 = { __expf(bf2f(sp[l32])), __expf(bf2f(sp[stride + l32])) };
        *reinterpret_cast<float2*>(&elp[h][0][l32][0]) = e2;
        if (l32 < 8) {
            float2 f2 = { __expf(bf2f(sp[32 + l32])),
                          __expf(bf2f(sp[stride + 32 + l32])) };
            *reinterpret_cast<float2*>(&elp[h][0][32 + l32][0]) = f2;
        }
    }

    for (int u = 0; u < CLEN / 2; ++u) {
        const float* eb = &elp[h][u & 1][0][0];
        // prefetch+stage E for steps 2u+2, 2u+3 (guarded)
        if (u + 1 < CLEN / 2) {
            const ushort* r2 = sp + (long)(2 * u + 2) * stride;
            const ushort* r3 = sp + (long)(2 * u + 3) * stride;
            float2 e2 = { __expf(bf2f(r2[l32])), __expf(bf2f(r3[l32])) };
            *reinterpret_cast<float2*>(&elp[h][(u + 1) & 1][l32][0]) = e2;
            if (l32 < 8) {
                float2 f2 = { __expf(bf2f(r2[32 + l32])),
                              __expf(bf2f(r3[32 + l32])) };
                *reinterpret_cast<float2*>(&elp[h][(u + 1) & 1][32 + l32][0]) = f2;
            }
        }
        // 5 vector reads serve BOTH steps
        const float4 rA = *reinterpret_cast<const float4*>(eb + (4 * d) * 2);
        const float4 rB = *reinterpret_cast<const float4*>(eb + (4 * d + 2) * 2);
        const float4 rC = *reinterpret_cast<const float4*>(eb + (16 + 4 * d) * 2);
        const float4 rD = *reinterpret_cast<const float4*>(eb + (16 + 4 * d + 2) * 2);
        const float4 rE = *reinterpret_cast<const float4*>(eb + (32 + 2 * d) * 2);

        // ---- step t = 2u (parity 0): components .x/.z ----
        {
            float v0 = fmaf(Plo, rA.x, Phi * rC.x);
            float v1 = fmaf(Plo, rA.z, Phi * rC.z);
            float v2 = fmaf(Plo, rB.x, Phi * rD.x);
            float v3 = fmaf(Plo, rB.z, Phi * rD.z);
            v0 = add_x2(add_x1(v0));
            v1 = add_x2(add_x1(v1));
            v2 = add_x2(add_x1(v2));
            v3 = add_x2(add_x1(v3));
            const float PhiN = fmaf(Plo, rE.x, Phi * rE.z);
            const float pa_ = (d & 1) ? v1 : v0;
            const float pb_ = (d & 1) ? v3 : v2;
            Plo = (d & 2) ? pb_ : pa_;
            Phi = PhiN;
        }
        // ---- step t = 2u+1 (parity 1): components .y/.w ----
        {
            float v0 = fmaf(Plo, rA.y, Phi * rC.y);
            float v1 = fmaf(Plo, rA.w, Phi * rC.w);
            float v2 = fmaf(Plo, rB.y, Phi * rD.y);
            float v3 = fmaf(Plo, rB.w, Phi * rD.w);
            v0 = add_x2(add_x1(v0));
            v1 = add_x2(add_x1(v1));
            v2 = add_x2(add_x1(v2));
            v3 = add_x2(add_x1(v3));
            const float PhiN = fmaf(Plo, rE.y, Phi * rE.w);
            const float pa_ = (d & 1) ? v1 : v0;
            const float pb_ = (d & 1) ? v3 : v2;
            Plo = (d & 2) ? pb_ : pa_;
            Phi = PhiN;
        }
        if (u & 1) {   // t = 4k+3: exact pow2 rescale, per-quad
            const float Mx = fmax_x2(fmax_x1(fmaxf(Plo, Phi)));
            const int ex = ((__float_as_int(Mx) >> 23) & 255) - 127;
            const float s = __int_as_float((unsigned)(127 - ex) << 23);
            Plo *= s;
            Phi *= s;
            scale += ex;
        }
    }
    const float base = (float)scale * 0.6931471805599453f;
    float* gb = gbuf + ((long)(n * CHUNKS + ch)) * 64;
    gb[q * 8 + d] = __logf(Plo) + base;       // G[d][col]
    gb[q * 8 + 4 + d] = __logf(Phi) + base;   // G[4+d][col]
}

// ---------------- butterfly lse helpers for kC ----------------
__device__ inline float lse8(float v) {
    const float m = max8(v);
    return m + __logf(sum8(__expf(v - m)));
}
__device__ inline float lse64(float v) {
    float m = v;
#pragma unroll
    for (int d = 1; d < 64; d <<= 1) m = fmaxf(m, __shfl_xor(m, d));
    float e = __expf(v - m);
#pragma unroll
    for (int d = 1; d < 64; d <<= 1) e += __shfl_xor(e, d);
    return m + __logf(e);
}

// ---------------- Kernel C: fold chunk matrices, emit logZ/T -------------
__global__ __launch_bounds__(64) void kC_combine(const float* __restrict__ gbuf,
                                                 float* __restrict__ logZT) {
    const int n = blockIdx.x;
    const int l = threadIdx.x;
    const int gi = (l & 7) * 8 + (l >> 3);
    float g[CHUNKS];
#pragma unroll
    for (int c = 0; c < CHUNKS; ++c)
        g[c] = gbuf[((long)(n * CHUNKS + c)) * 64 + gi];
    float u = -logf(8.f);
#pragma unroll
    for (int c = 0; c < CHUNKS; ++c) {
        const float nu = lse8(g[c] + u);
        u = __shfl(nu, ((l & 7) << 3) | (l >> 3));
    }
    const float z = lse64(u);
    if (l == 0) logZT[n] = z / (float)TT;
}

// ---------------- Kernel D: bf16 scores -> final f32 output --------------
__global__ __launch_bounds__(128) void kD_final(const ushort* __restrict__ sc,
                                                const float* __restrict__ logZT,
                                                float* __restrict__ out) {
    __shared__ float dout[128 * SOUT];
    const int tid = threadIdx.x;
    const long row0 = (long)blockIdx.x * 128;
    const long row = row0 + tid;
    const int n = (int)(row & (NN - 1));
    const float z = logZT[n];
    const ushort* srow = sc + row * SOUT;
    float st[48];
#pragma unroll
    for (int i = 0; i < 6; ++i) {
        const uint4 qv = reinterpret_cast<const uint4*>(srow)[i];
        const unsigned wv[4] = {qv.x, qv.y, qv.z, qv.w};
#pragma unroll
        for (int t = 0; t < 4; ++t) {
            st[8 * i + 2 * t]     = __uint_as_float(wv[t] << 16);
            st[8 * i + 2 * t + 1] = __uint_as_float(wv[t] & 0xffff0000u);
        }
    }
    float* a = &dout[tid * SOUT];
#pragma unroll
    for (int c = 0; c < 40; ++c) a[c] = st[sidx(c)] - z;
    const float y40 = st[40], y41 = st[41], y42 = st[42], y43 = st[43], y44 = st[44];
    const float m3 = fmaxf(fmaxf(y40, y41), y42);
    const float l3 = m3 + __logf(__expf(y40 - m3) + __expf(y41 - m3) + __expf(y42 - m3));
    a[40] = y40 - l3; a[41] = y41 - l3; a[42] = y42 - l3;
    const float mA = fmaxf(y40, y43);
    const float lA = mA + __logf(__expf(y40 - mA) + __expf(y43 - mA));
    a[43] = y40 - lA; a[44] = y43 - lA;
    a[45] = 0.f;
    const float mB = fmaxf(y40, y44);
    const float lB = mB + __logf(__expf(y40 - mB) + __expf(y44 - mB));
    a[46] = y40 - lB; a[47] = y44 - lB;
    __syncthreads();
    const float4* sf = reinterpret_cast<const float4*>(dout);
    float4* df = reinterpret_cast<float4*>(out + row0 * SOUT);
#pragma unroll
    for (int kq = 0; kq < 12; ++kq)
        df[kq * 128 + tid] = sf[kq * 128 + tid];
}

extern "C" void kernel_launch(void* const* d_in, const int* in_sizes, int n_in,
                              void* d_out, int out_size, void* d_ws, size_t ws_size,
                              hipStream_t stream) {
    const float* x = (const float*)d_in[0];
    const float* W = (const float*)d_in[1];
    const float* b = (const float*)d_in[2];
    float* out = (float*)d_out;

    ushort* sc   = (ushort*)d_ws;                          // 49.15 MB
    float* gbuf  = (float*)((char*)d_ws + 49152000);       // 2.62 MB
    float* logZT = gbuf + (long)NN * CHUNKS * 64;          // 256 f32
    float* b48   = logZT + NN;                             // 48 f32
    ushort* Whi  = (ushort*)(b48 + SOUT);                  // 24 KB

    hipLaunchKernelGGL(kPrep, dim3(SOUT), dim3(DD), 0, stream, W, b, Whi, b48);
    hipLaunchKernelGGL(kA_mfma, dim3((TT * NN) / 128), dim3(512), 0, stream, x, Whi, b48, sc);
    hipLaunchKernelGGL(kB_scan, dim3(NN, CHUNKS / 2), dim3(64), 0, stream, sc, gbuf);
    hipLaunchKernelGGL(kC_combine, dim3(NN), dim3(64), 0, stream, gbuf, logZT);
    hipLaunchKernelGGL(kD_final, dim3((TT * NN) / 128), dim3(128), 0, stream, sc, logZT, out);
}

// Round 19
// 179.303 us; speedup vs baseline: 9.1534x; 1.0397x over previous
//
#include <hip/hip_runtime.h>
#include <hip/hip_bf16.h>
#include <math.h>

#define TT 2000
#define NN 256
#define DD 256
#define SS 45
#define SOUT 48
#define NTRANS_C 40
#define CHUNKS 40
#define CLEN 50   // TT / CHUNKS
#define BK 32     // x K-chunk (floats)
#define NCH (DD / BK)   // 8 chunks
#define XPAD 40   // bf16 x-tile row stride (ushorts)

typedef __attribute__((ext_vector_type(8))) short bf16x8;
typedef __attribute__((ext_vector_type(4))) float f32x4;

__device__ inline ushort f2bf_rne(float f) {
    unsigned u = __float_as_uint(f);
    unsigned r = u + 0x7fffu + ((u >> 16) & 1u);
    return (ushort)(r >> 16);
}
__device__ __forceinline__ int cvtpk(float lo, float hi) {
    int r;
    asm("v_cvt_pk_bf16_f32 %0, %1, %2" : "=v"(r) : "v"(lo), "v"(hi));
    return r;
}
__device__ __forceinline__ float bf2f(ushort h) {
    return __uint_as_float(((unsigned)h) << 16);
}
__device__ __host__ __forceinline__ constexpr int sidx(int c) {
    return (c < 32) ? (4 * (c & 7) + (c >> 3))
         : (c < 36) ? (32 + 2 * (c - 32))
         : (c < 40) ? (32 + 2 * (c - 36) + 1)
         : c;
}
__device__ __forceinline__ int swz_idx(int s, int koff) {
    return s * DD + ((((koff >> 3) ^ (s & 7)) << 3) | (koff & 7));
}

// ---------------- Prep: W -> bf16 (RNE), pad to 48 rows; pad b ----------
__global__ __launch_bounds__(256) void kPrep(const float* __restrict__ W,
                                             const float* __restrict__ b,
                                             ushort* __restrict__ Whi,
                                             float* __restrict__ b48) {
    const int s = blockIdx.x;
    const int k = threadIdx.x;
    const float wv = (s < SS) ? W[s * DD + k] : 0.f;
    Whi[s * DD + k] = f2bf_rne(wv);
    if (k == 0) b48[s] = (s < SS) ? b[s] : 0.f;
}

// ---------------- Kernel A: exact R14/R18 config --------------------------
__global__ __launch_bounds__(512, 6) void kA_mfma(const float* __restrict__ x,
                                                  const ushort* __restrict__ Whi,
                                                  const float* __restrict__ b48,
                                                  ushort* __restrict__ sc) {
    __shared__ ushort Wl[SOUT * DD];
    __shared__ ushort xw[8][16 * XPAD];
    const int tid = threadIdx.x;
    for (int idx = tid; idx < SOUT * (DD / 8); idx += 512) {
        const int s = idx >> 5;
        const int c8 = (idx & 31) * 8;
        const uint4 v = *reinterpret_cast<const uint4*>(Whi + s * DD + c8);
        *reinterpret_cast<uint4*>(&Wl[swz_idx(s, c8)]) = v;
    }
    __syncthreads();

    const int l = tid & 63, w = tid >> 6;
    const long m0 = (long)blockIdx.x * 128;
    const int r16 = l & 15;
    const int kg = l >> 4;
    const int lrow = l >> 3;
    const int lcol = (l & 7) * 4;
    const float* xp = x + (m0 + w * 16 + lrow) * DD + lcol;
    const float* xq = xp + 8 * DD;
    ushort* xs = xw[w];
    int2* xw0 = reinterpret_cast<int2*>(&xs[lrow * XPAD + lcol]);
    int2* xw1 = reinterpret_cast<int2*>(&xs[(lrow + 8) * XPAD + lcol]);
    const bf16x8* xrd = reinterpret_cast<const bf16x8*>(&xs[r16 * XPAD + kg * 8]);

    f32x4 acc[3] = {{0, 0, 0, 0}, {0, 0, 0, 0}, {0, 0, 0, 0}};

    float4 pf[2][2];
    pf[0][0] = *reinterpret_cast<const float4*>(xp + 0);
    pf[0][1] = *reinterpret_cast<const float4*>(xq + 0);
    pf[1][0] = *reinterpret_cast<const float4*>(xp + BK);
    pf[1][1] = *reinterpret_cast<const float4*>(xq + BK);

#pragma unroll
    for (int c = 0; c < NCH; ++c) {
        const float4 pa = pf[c & 1][0];
        const float4 qa = pf[c & 1][1];
        xw0->x = cvtpk(pa.x, pa.y);
        xw0->y = cvtpk(pa.z, pa.w);
        xw1->x = cvtpk(qa.x, qa.y);
        xw1->y = cvtpk(qa.z, qa.w);
        if (c + 2 < NCH) {
            pf[c & 1][0] = *reinterpret_cast<const float4*>(xp + (c + 2) * BK);
            pf[c & 1][1] = *reinterpret_cast<const float4*>(xq + (c + 2) * BK);
        }
        __builtin_amdgcn_sched_barrier(0);
        const bf16x8 a = *xrd;
        const int koff = c * BK + kg * 8;
        const bf16x8 b0 = *reinterpret_cast<const bf16x8*>(&Wl[swz_idx(0 * 16 + r16, koff)]);
        const bf16x8 b1 = *reinterpret_cast<const bf16x8*>(&Wl[swz_idx(1 * 16 + r16, koff)]);
        const bf16x8 b2 = *reinterpret_cast<const bf16x8*>(&Wl[swz_idx(2 * 16 + r16, koff)]);
        acc[0] = __builtin_amdgcn_mfma_f32_16x16x32_bf16(a, b0, acc[0], 0, 0, 0);
        acc[1] = __builtin_amdgcn_mfma_f32_16x16x32_bf16(a, b1, acc[1], 0, 0, 0);
        acc[2] = __builtin_amdgcn_mfma_f32_16x16x32_bf16(a, b2, acc[2], 0, 0, 0);
    }

    __syncthreads();
    ushort* se = Wl;
#pragma unroll
    for (int jt = 0; jt < 3; ++jt) {
        const int col = jt * 16 + r16;
        const float bias = b48[col];
        int si;
        if (jt < 2) si = 4 * (col & 7) + (col >> 3);
        else if (r16 < 8) si = (r16 < 4) ? (32 + 2 * r16) : (32 + 2 * (r16 - 4) + 1);
        else si = 40 + (r16 - 8);
#pragma unroll
        for (int r = 0; r < 4; ++r) {
            const int lr = w * 16 + kg * 4 + r;
            const float y = acc[jt][r] + bias;
            float v;
            if (col < NTRANS_C) {
                const float e = __expf(2.f * y);
                v = 5.f * (1.f - 2.f / (e + 1.f));
            } else {
                v = y;
            }
            se[lr * SOUT + si] = f2bf_rne(v);
        }
    }
    __syncthreads();
    const uint4* su = reinterpret_cast<const uint4*>(se);
    uint4* du = reinterpret_cast<uint4*>(sc + m0 * SOUT);
    du[tid] = su[tid];
    if (tid < 256) du[512 + tid] = su[512 + tid];
}

// ---------------- DPP / swizzle cross-lane helpers -----------------------
#define DPP_XOR1 0xB1
#define DPP_XOR2 0x4E

__device__ inline float fmax_x1(float v) {
    const int d = __builtin_amdgcn_mov_dpp(__float_as_int(v), DPP_XOR1, 0xF, 0xF, true);
    return fmaxf(v, __int_as_float(d));
}
__device__ inline float fmax_x2(float v) {
    const int d = __builtin_amdgcn_mov_dpp(__float_as_int(v), DPP_XOR2, 0xF, 0xF, true);
    return fmaxf(v, __int_as_float(d));
}
__device__ inline float add_x1(float v) {
    const int d = __builtin_amdgcn_mov_dpp(__float_as_int(v), DPP_XOR1, 0xF, 0xF, true);
    return v + __int_as_float(d);
}
__device__ inline float add_x2(float v) {
    const int d = __builtin_amdgcn_mov_dpp(__float_as_int(v), DPP_XOR2, 0xF, 0xF, true);
    return v + __int_as_float(d);
}
__device__ inline float swz4(float v) {   // lane ^ 4
    return __int_as_float(__builtin_amdgcn_ds_swizzle(__float_as_int(v), 0x101F));
}
__device__ inline float fmax_x4(float v) { return fmaxf(v, swz4(v)); }
__device__ inline float add_x4(float v) { return v + swz4(v); }
__device__ inline float sum8(float v) { return add_x4(add_x2(add_x1(v))); }
__device__ inline float max8(float v) { return fmax_x4(fmax_x2(fmax_x1(v))); }

// ---------------- Kernel B: pair-layout scan, deep score prefetch --------
// R18 residual: score loads are L3-latency (~600cy) with 1-iter cover and
// only 16 waves/CU. Now: (1) 3-iteration register score-queue (full unroll,
// compile-time indices) covers the L3 latency; (2) 256-thr blocks (4 waves,
// 8 chunks) -> 24 waves/CU. Math bit-identical to R18.
__global__ __launch_bounds__(256) void kB_scan(const ushort* __restrict__ sc,
                                               float* __restrict__ gbuf) {
    __shared__ float elp[8][2][48][2];   // 24.6 KB: [half][buf][slot][par]
    const int n = blockIdx.x;
    const int tid = threadIdx.x;
    const int h = tid >> 5;          // 0..7 -> chunk within block
    const int l32 = tid & 31;
    const int d = l32 & 3;           // state index within quad
    const int q = l32 >> 2;          // column 0..7
    const int ch = blockIdx.y * 8 + h;
    const long stride = (long)NN * SOUT;
    const ushort* sp = sc + ((long)(ch * CLEN) * NN + n) * SOUT;   // row t=0

    float Plo = (d == q) ? 1.f : 0.f;        // M[d][col]
    float Phi = (4 + d == q) ? 1.f : 0.f;    // M[4+d][col]
    int scale = 0;

    // stage E for t=0,1 into u-parity buffer 0
    {
        float2 e2 = { __expf(bf2f(sp[l32])), __expf(bf2f(sp[stride + l32])) };
        *reinterpret_cast<float2*>(&elp[h][0][l32][0]) = e2;
        if (l32 < 8) {
            float2 f2 = { __expf(bf2f(sp[32 + l32])),
                          __expf(bf2f(sp[stride + 32 + l32])) };
            *reinterpret_cast<float2*>(&elp[h][0][32 + l32][0]) = f2;
        }
    }

    // register score-queue: slot v holds raw scores of steps 2v+2, 2v+3
    ushort qa[3], qb[3], qc[3], qd[3];
#pragma unroll
    for (int v = 0; v < 2; ++v) {   // prologue: fill v=0,1
        const ushort* rA_ = sp + (long)(2 * v + 2) * stride;
        const ushort* rB_ = sp + (long)(2 * v + 3) * stride;
        qa[v] = rA_[l32];
        qb[v] = rB_[l32];
        if (l32 < 8) { qc[v] = rA_[32 + l32]; qd[v] = rB_[32 + l32]; }
    }

#pragma unroll
    for (int u = 0; u < CLEN / 2; ++u) {
        // E-write for steps 2u+2, 2u+3 from queue slot u (loaded >=2 iters ago)
        if (u <= CLEN / 2 - 2) {
            float2 e2 = { __expf(bf2f(qa[u % 3])), __expf(bf2f(qb[u % 3])) };
            *reinterpret_cast<float2*>(&elp[h][(u + 1) & 1][l32][0]) = e2;
            if (l32 < 8) {
                float2 f2 = { __expf(bf2f(qc[u % 3])), __expf(bf2f(qd[u % 3])) };
                *reinterpret_cast<float2*>(&elp[h][(u + 1) & 1][32 + l32][0]) = f2;
            }
        }
        // refill queue slot u+2 (scores of steps 2u+6, 2u+7), 2-3 iters ahead
        if (u + 2 <= CLEN / 2 - 2) {
            const ushort* rA_ = sp + (long)(2 * u + 6) * stride;
            const ushort* rB_ = sp + (long)(2 * u + 7) * stride;
            qa[(u + 2) % 3] = rA_[l32];
            qb[(u + 2) % 3] = rB_[l32];
            if (l32 < 8) { qc[(u + 2) % 3] = rA_[32 + l32]; qd[(u + 2) % 3] = rB_[32 + l32]; }
        }
        // 5 vector reads serve BOTH steps
        const float* eb = &elp[h][u & 1][0][0];
        const float4 rA = *reinterpret_cast<const float4*>(eb + (4 * d) * 2);
        const float4 rB = *reinterpret_cast<const float4*>(eb + (4 * d + 2) * 2);
        const float4 rC = *reinterpret_cast<const float4*>(eb + (16 + 4 * d) * 2);
        const float4 rD = *reinterpret_cast<const float4*>(eb + (16 + 4 * d + 2) * 2);
        const float4 rE = *reinterpret_cast<const float4*>(eb + (32 + 2 * d) * 2);

        // ---- step t = 2u (parity 0): components .x/.z ----
        {
            float v0 = fmaf(Plo, rA.x, Phi * rC.x);
            float v1 = fmaf(Plo, rA.z, Phi * rC.z);
            float v2 = fmaf(Plo, rB.x, Phi * rD.x);
            float v3 = fmaf(Plo, rB.z, Phi * rD.z);
            v0 = add_x2(add_x1(v0));
            v1 = add_x2(add_x1(v1));
            v2 = add_x2(add_x1(v2));
            v3 = add_x2(add_x1(v3));
            const float PhiN = fmaf(Plo, rE.x, Phi * rE.z);
            const float pa_ = (d & 1) ? v1 : v0;
            const float pb_ = (d & 1) ? v3 : v2;
            Plo = (d & 2) ? pb_ : pa_;
            Phi = PhiN;
        }
        // ---- step t = 2u+1 (parity 1): components .y/.w ----
        {
            float v0 = fmaf(Plo, rA.y, Phi * rC.y);
            float v1 = fmaf(Plo, rA.w, Phi * rC.w);
            float v2 = fmaf(Plo, rB.y, Phi * rD.y);
            float v3 = fmaf(Plo, rB.w, Phi * rD.w);
            v0 = add_x2(add_x1(v0));
            v1 = add_x2(add_x1(v1));
            v2 = add_x2(add_x1(v2));
            v3 = add_x2(add_x1(v3));
            const float PhiN = fmaf(Plo, rE.y, Phi * rE.w);
            const float pa_ = (d & 1) ? v1 : v0;
            const float pb_ = (d & 1) ? v3 : v2;
            Plo = (d & 2) ? pb_ : pa_;
            Phi = PhiN;
        }
        if (u & 1) {   // t = 4k+3: exact pow2 rescale, per-quad
            const float Mx = fmax_x2(fmax_x1(fmaxf(Plo, Phi)));
            const int ex = ((__float_as_int(Mx) >> 23) & 255) - 127;
            const float s = __int_as_float((unsigned)(127 - ex) << 23);
            Plo *= s;
            Phi *= s;
            scale += ex;
        }
    }
    const float base = (float)scale * 0.6931471805599453f;
    float* gb = gbuf + ((long)(n * CHUNKS + ch)) * 64;
    gb[q * 8 + d] = __logf(Plo) + base;       // G[d][col]
    gb[q * 8 + 4 + d] = __logf(Phi) + base;   // G[4+d][col]
}

// ---------------- butterfly lse helpers for kC ----------------
__device__ inline float lse8(float v) {
    const float m = max8(v);
    return m + __logf(sum8(__expf(v - m)));
}
__device__ inline float lse64(float v) {
    float m = v;
#pragma unroll
    for (int d = 1; d < 64; d <<= 1) m = fmaxf(m, __shfl_xor(m, d));
    float e = __expf(v - m);
#pragma unroll
    for (int d = 1; d < 64; d <<= 1) e += __shfl_xor(e, d);
    return m + __logf(e);
}

// ---------------- Kernel C: fold chunk matrices, emit logZ/T -------------
__global__ __launch_bounds__(64) void kC_combine(const float* __restrict__ gbuf,
                                                 float* __restrict__ logZT) {
    const int n = blockIdx.x;
    const int l = threadIdx.x;
    const int gi = (l & 7) * 8 + (l >> 3);
    float g[CHUNKS];
#pragma unroll
    for (int c = 0; c < CHUNKS; ++c)
        g[c] = gbuf[((long)(n * CHUNKS + c)) * 64 + gi];
    float u = -logf(8.f);
#pragma unroll
    for (int c = 0; c < CHUNKS; ++c) {
        const float nu = lse8(g[c] + u);
        u = __shfl(nu, ((l & 7) << 3) | (l >> 3));
    }
    const float z = lse64(u);
    if (l == 0) logZT[n] = z / (float)TT;
}

// ---------------- Kernel D: bf16 scores -> final f32 output --------------
__global__ __launch_bounds__(128) void kD_final(const ushort* __restrict__ sc,
                                                const float* __restrict__ logZT,
                                                float* __restrict__ out) {
    __shared__ float dout[128 * SOUT];
    const int tid = threadIdx.x;
    const long row0 = (long)blockIdx.x * 128;
    const long row = row0 + tid;
    const int n = (int)(row & (NN - 1));
    const float z = logZT[n];
    const ushort* srow = sc + row * SOUT;
    float st[48];
#pragma unroll
    for (int i = 0; i < 6; ++i) {
        const uint4 qv = reinterpret_cast<const uint4*>(srow)[i];
        const unsigned wv[4] = {qv.x, qv.y, qv.z, qv.w};
#pragma unroll
        for (int t = 0; t < 4; ++t) {
            st[8 * i + 2 * t]     = __uint_as_float(wv[t] << 16);
            st[8 * i + 2 * t + 1] = __uint_as_float(wv[t] & 0xffff0000u);
        }
    }
    float* a = &dout[tid * SOUT];
#pragma unroll
    for (int c = 0; c < 40; ++c) a[c] = st[sidx(c)] - z;
    const float y40 = st[40], y41 = st[41], y42 = st[42], y43 = st[43], y44 = st[44];
    const float m3 = fmaxf(fmaxf(y40, y41), y42);
    const float l3 = m3 + __logf(__expf(y40 - m3) + __expf(y41 - m3) + __expf(y42 - m3));
    a[40] = y40 - l3; a[41] = y41 - l3; a[42] = y42 - l3;
    const float mA = fmaxf(y40, y43);
    const float lA = mA + __logf(__expf(y40 - mA) + __expf(y43 - mA));
    a[43] = y40 - lA; a[44] = y43 - lA;
    a[45] = 0.f;
    const float mB = fmaxf(y40, y44);
    const float lB = mB + __logf(__expf(y40 - mB) + __expf(y44 - mB));
    a[46] = y40 - lB; a[47] = y44 - lB;
    __syncthreads();
    const float4* sf = reinterpret_cast<const float4*>(dout);
    float4* df = reinterpret_cast<float4*>(out + row0 * SOUT);
#pragma unroll
    for (int kq = 0; kq < 12; ++kq)
        df[kq * 128 + tid] = sf[kq * 128 + tid];
}

extern "C" void kernel_launch(void* const* d_in, const int* in_sizes, int n_in,
                              void* d_out, int out_size, void* d_ws, size_t ws_size,
                              hipStream_t stream) {
    const float* x = (const float*)d_in[0];
    const float* W = (const float*)d_in[1];
    const float* b = (const float*)d_in[2];
    float* out = (float*)d_out;

    ushort* sc   = (ushort*)d_ws;                          // 49.15 MB
    float* gbuf  = (float*)((char*)d_ws + 49152000);       // 2.62 MB
    float* logZT = gbuf + (long)NN * CHUNKS * 64;          // 256 f32
    float* b48   = logZT + NN;                             // 48 f32
    ushort* Whi  = (ushort*)(b48 + SOUT);                  // 24 KB

    hipLaunchKernelGGL(kPrep, dim3(SOUT), dim3(DD), 0, stream, W, b, Whi, b48);
    hipLaunchKernelGGL(kA_mfma, dim3((TT * NN) / 128), dim3(512), 0, stream, x, Whi, b48, sc);
    hipLaunchKernelGGL(kB_scan, dim3(NN, CHUNKS / 8), dim3(256), 0, stream, sc, gbuf);
    hipLaunchKernelGGL(kC_combine, dim3(NN), dim3(64), 0, stream, gbuf, logZT);
    hipLaunchKernelGGL(kD_final, dim3((TT * NN) / 128), dim3(128), 0, stream, sc, logZT, out);
}

// Round 20
// 176.783 us; speedup vs baseline: 9.2840x; 1.0143x over previous
//
#include <hip/hip_runtime.h>
#include <hip/hip_bf16.h>
#include <math.h>

#define TT 2000
#define NN 256
#define DD 256
#define SS 45
#define SOUT 48
#define NTRANS_C 40
#define CHUNKS 40
#define CLEN 50   // TT / CHUNKS
#define BK 32     // x K-chunk (floats)
#define NCH (DD / BK)   // 8 chunks
#define XPAD 40   // bf16 x-tile row stride (ushorts)

typedef __attribute__((ext_vector_type(8))) short bf16x8;
typedef __attribute__((ext_vector_type(4))) float f32x4;

__device__ inline ushort f2bf_rne(float f) {
    unsigned u = __float_as_uint(f);
    unsigned r = u + 0x7fffu + ((u >> 16) & 1u);
    return (ushort)(r >> 16);
}
__device__ __forceinline__ int cvtpk(float lo, float hi) {
    int r;
    asm("v_cvt_pk_bf16_f32 %0, %1, %2" : "=v"(r) : "v"(lo), "v"(hi));
    return r;
}
__device__ __forceinline__ float bf2f(ushort h) {
    return __uint_as_float(((unsigned)h) << 16);
}
__device__ __host__ __forceinline__ constexpr int sidx(int c) {
    return (c < 32) ? (4 * (c & 7) + (c >> 3))
         : (c < 36) ? (32 + 2 * (c - 32))
         : (c < 40) ? (32 + 2 * (c - 36) + 1)
         : c;
}
__device__ __forceinline__ int swz_idx(int s, int koff) {
    return s * DD + ((((koff >> 3) ^ (s & 7)) << 3) | (koff & 7));
}

// ---------------- Prep: W -> bf16 (RNE), pad to 48 rows; pad b ----------
__global__ __launch_bounds__(256) void kPrep(const float* __restrict__ W,
                                             const float* __restrict__ b,
                                             ushort* __restrict__ Whi,
                                             float* __restrict__ b48) {
    const int s = blockIdx.x;
    const int k = threadIdx.x;
    const float wv = (s < SS) ? W[s * DD + k] : 0.f;
    Whi[s * DD + k] = f2bf_rne(wv);
    if (k == 0) b48[s] = (s < SS) ? b[s] : 0.f;
}

// ---------------- Kernel A: R14 structure, 3-deep x prefetch -------------
__global__ __launch_bounds__(512, 6) void kA_mfma(const float* __restrict__ x,
                                                  const ushort* __restrict__ Whi,
                                                  const float* __restrict__ b48,
                                                  ushort* __restrict__ sc) {
    __shared__ ushort Wl[SOUT * DD];
    __shared__ ushort xw[8][16 * XPAD];
    const int tid = threadIdx.x;
    for (int idx = tid; idx < SOUT * (DD / 8); idx += 512) {
        const int s = idx >> 5;
        const int c8 = (idx & 31) * 8;
        const uint4 v = *reinterpret_cast<const uint4*>(Whi + s * DD + c8);
        *reinterpret_cast<uint4*>(&Wl[swz_idx(s, c8)]) = v;
    }
    __syncthreads();

    const int l = tid & 63, w = tid >> 6;
    const long m0 = (long)blockIdx.x * 128;
    const int r16 = l & 15;
    const int kg = l >> 4;
    const int lrow = l >> 3;
    const int lcol = (l & 7) * 4;
    const float* xp = x + (m0 + w * 16 + lrow) * DD + lcol;
    const float* xq = xp + 8 * DD;
    ushort* xs = xw[w];
    int2* xw0 = reinterpret_cast<int2*>(&xs[lrow * XPAD + lcol]);
    int2* xw1 = reinterpret_cast<int2*>(&xs[(lrow + 8) * XPAD + lcol]);
    const bf16x8* xrd = reinterpret_cast<const bf16x8*>(&xs[r16 * XPAD + kg * 8]);

    f32x4 acc[3] = {{0, 0, 0, 0}, {0, 0, 0, 0}, {0, 0, 0, 0}};

    // 3-deep register prefetch (load-to-use distance = 3 iterations)
    float4 pf[3][2];
#pragma unroll
    for (int v = 0; v < 3; ++v) {
        pf[v][0] = *reinterpret_cast<const float4*>(xp + v * BK);
        pf[v][1] = *reinterpret_cast<const float4*>(xq + v * BK);
    }

#pragma unroll
    for (int c = 0; c < NCH; ++c) {
        const float4 pa = pf[c % 3][0];
        const float4 qa = pf[c % 3][1];
        xw0->x = cvtpk(pa.x, pa.y);
        xw0->y = cvtpk(pa.z, pa.w);
        xw1->x = cvtpk(qa.x, qa.y);
        xw1->y = cvtpk(qa.z, qa.w);
        if (c + 3 < NCH) {   // refill the slot just consumed
            pf[c % 3][0] = *reinterpret_cast<const float4*>(xp + (c + 3) * BK);
            pf[c % 3][1] = *reinterpret_cast<const float4*>(xq + (c + 3) * BK);
        }
        __builtin_amdgcn_sched_barrier(0);
        const bf16x8 a = *xrd;
        const int koff = c * BK + kg * 8;
        const bf16x8 b0 = *reinterpret_cast<const bf16x8*>(&Wl[swz_idx(0 * 16 + r16, koff)]);
        const bf16x8 b1 = *reinterpret_cast<const bf16x8*>(&Wl[swz_idx(1 * 16 + r16, koff)]);
        const bf16x8 b2 = *reinterpret_cast<const bf16x8*>(&Wl[swz_idx(2 * 16 + r16, koff)]);
        acc[0] = __builtin_amdgcn_mfma_f32_16x16x32_bf16(a, b0, acc[0], 0, 0, 0);
        acc[1] = __builtin_amdgcn_mfma_f32_16x16x32_bf16(a, b1, acc[1], 0, 0, 0);
        acc[2] = __builtin_amdgcn_mfma_f32_16x16x32_bf16(a, b2, acc[2], 0, 0, 0);
    }

    __syncthreads();
    ushort* se = Wl;
#pragma unroll
    for (int jt = 0; jt < 3; ++jt) {
        const int col = jt * 16 + r16;
        const float bias = b48[col];
        int si;
        if (jt < 2) si = 4 * (col & 7) + (col >> 3);
        else if (r16 < 8) si = (r16 < 4) ? (32 + 2 * r16) : (32 + 2 * (r16 - 4) + 1);
        else si = 40 + (r16 - 8);
#pragma unroll
        for (int r = 0; r < 4; ++r) {
            const int lr = w * 16 + kg * 4 + r;
            const float y = acc[jt][r] + bias;
            float v;
            if (col < NTRANS_C) {
                const float e = __expf(2.f * y);
                v = 5.f * (1.f - 2.f / (e + 1.f));
            } else {
                v = y;
            }
            se[lr * SOUT + si] = f2bf_rne(v);
        }
    }
    __syncthreads();
    const uint4* su = reinterpret_cast<const uint4*>(se);
    uint4* du = reinterpret_cast<uint4*>(sc + m0 * SOUT);
    du[tid] = su[tid];
    if (tid < 256) du[512 + tid] = su[512 + tid];
}

// ---------------- DPP / swizzle cross-lane helpers -----------------------
#define DPP_XOR1 0xB1
#define DPP_XOR2 0x4E

__device__ inline float fmax_x1(float v) {
    const int d = __builtin_amdgcn_mov_dpp(__float_as_int(v), DPP_XOR1, 0xF, 0xF, true);
    return fmaxf(v, __int_as_float(d));
}
__device__ inline float fmax_x2(float v) {
    const int d = __builtin_amdgcn_mov_dpp(__float_as_int(v), DPP_XOR2, 0xF, 0xF, true);
    return fmaxf(v, __int_as_float(d));
}
__device__ inline float add_x1(float v) {
    const int d = __builtin_amdgcn_mov_dpp(__float_as_int(v), DPP_XOR1, 0xF, 0xF, true);
    return v + __int_as_float(d);
}
__device__ inline float add_x2(float v) {
    const int d = __builtin_amdgcn_mov_dpp(__float_as_int(v), DPP_XOR2, 0xF, 0xF, true);
    return v + __int_as_float(d);
}
__device__ inline float swz4(float v) {   // lane ^ 4
    return __int_as_float(__builtin_amdgcn_ds_swizzle(__float_as_int(v), 0x101F));
}
__device__ inline float fmax_x4(float v) { return fmaxf(v, swz4(v)); }
__device__ inline float add_x4(float v) { return v + swz4(v); }
__device__ inline float sum8(float v) { return add_x4(add_x2(add_x1(v))); }
__device__ inline float max8(float v) { return fmax_x4(fmax_x2(fmax_x1(v))); }

// ---------------- Kernel B: pair-layout scan, deep score prefetch --------
__global__ __launch_bounds__(256) void kB_scan(const ushort* __restrict__ sc,
                                               float* __restrict__ gbuf) {
    __shared__ float elp[8][2][48][2];   // 24.6 KB: [half][buf][slot][par]
    const int n = blockIdx.x;
    const int tid = threadIdx.x;
    const int h = tid >> 5;          // 0..7 -> chunk within block
    const int l32 = tid & 31;
    const int d = l32 & 3;           // state index within quad
    const int q = l32 >> 2;          // column 0..7
    const int ch = blockIdx.y * 8 + h;
    const long stride = (long)NN * SOUT;
    const ushort* sp = sc + ((long)(ch * CLEN) * NN + n) * SOUT;   // row t=0

    float Plo = (d == q) ? 1.f : 0.f;        // M[d][col]
    float Phi = (4 + d == q) ? 1.f : 0.f;    // M[4+d][col]
    int scale = 0;

    // stage E for t=0,1 into u-parity buffer 0
    {
        float2 e2 = { __expf(bf2f(sp[l32])), __expf(bf2f(sp[stride + l32])) };
        *reinterpret_cast<float2*>(&elp[h][0][l32][0]) = e2;
        if (l32 < 8) {
            float2 f2 = { __expf(bf2f(sp[32 + l32])),
                          __expf(bf2f(sp[stride + 32 + l32])) };
            *reinterpret_cast<float2*>(&elp[h][0][32 + l32][0]) = f2;
        }
    }

    // register score-queue: slot v holds raw scores of steps 2v+2, 2v+3
    ushort qa[3], qb[3], qc[3], qd[3];
#pragma unroll
    for (int v = 0; v < 2; ++v) {
        const ushort* rA_ = sp + (long)(2 * v + 2) * stride;
        const ushort* rB_ = sp + (long)(2 * v + 3) * stride;
        qa[v] = rA_[l32];
        qb[v] = rB_[l32];
        if (l32 < 8) { qc[v] = rA_[32 + l32]; qd[v] = rB_[32 + l32]; }
    }

#pragma unroll
    for (int u = 0; u < CLEN / 2; ++u) {
        if (u <= CLEN / 2 - 2) {
            float2 e2 = { __expf(bf2f(qa[u % 3])), __expf(bf2f(qb[u % 3])) };
            *reinterpret_cast<float2*>(&elp[h][(u + 1) & 1][l32][0]) = e2;
            if (l32 < 8) {
                float2 f2 = { __expf(bf2f(qc[u % 3])), __expf(bf2f(qd[u % 3])) };
                *reinterpret_cast<float2*>(&elp[h][(u + 1) & 1][32 + l32][0]) = f2;
            }
        }
        if (u + 2 <= CLEN / 2 - 2) {
            const ushort* rA_ = sp + (long)(2 * u + 6) * stride;
            const ushort* rB_ = sp + (long)(2 * u + 7) * stride;
            qa[(u + 2) % 3] = rA_[l32];
            qb[(u + 2) % 3] = rB_[l32];
            if (l32 < 8) { qc[(u + 2) % 3] = rA_[32 + l32]; qd[(u + 2) % 3] = rB_[32 + l32]; }
        }
        const float* eb = &elp[h][u & 1][0][0];
        const float4 rA = *reinterpret_cast<const float4*>(eb + (4 * d) * 2);
        const float4 rB = *reinterpret_cast<const float4*>(eb + (4 * d + 2) * 2);
        const float4 rC = *reinterpret_cast<const float4*>(eb + (16 + 4 * d) * 2);
        const float4 rD = *reinterpret_cast<const float4*>(eb + (16 + 4 * d + 2) * 2);
        const float4 rE = *reinterpret_cast<const float4*>(eb + (32 + 2 * d) * 2);

        {
            float v0 = fmaf(Plo, rA.x, Phi * rC.x);
            float v1 = fmaf(Plo, rA.z, Phi * rC.z);
            float v2 = fmaf(Plo, rB.x, Phi * rD.x);
            float v3 = fmaf(Plo, rB.z, Phi * rD.z);
            v0 = add_x2(add_x1(v0));
            v1 = add_x2(add_x1(v1));
            v2 = add_x2(add_x1(v2));
            v3 = add_x2(add_x1(v3));
            const float PhiN = fmaf(Plo, rE.x, Phi * rE.z);
            const float pa_ = (d & 1) ? v1 : v0;
            const float pb_ = (d & 1) ? v3 : v2;
            Plo = (d & 2) ? pb_ : pa_;
            Phi = PhiN;
        }
        {
            float v0 = fmaf(Plo, rA.y, Phi * rC.y);
            float v1 = fmaf(Plo, rA.w, Phi * rC.w);
            float v2 = fmaf(Plo, rB.y, Phi * rD.y);
            float v3 = fmaf(Plo, rB.w, Phi * rD.w);
            v0 = add_x2(add_x1(v0));
            v1 = add_x2(add_x1(v1));
            v2 = add_x2(add_x1(v2));
            v3 = add_x2(add_x1(v3));
            const float PhiN = fmaf(Plo, rE.y, Phi * rE.w);
            const float pa_ = (d & 1) ? v1 : v0;
            const float pb_ = (d & 1) ? v3 : v2;
            Plo = (d & 2) ? pb_ : pa_;
            Phi = PhiN;
        }
        if (u & 1) {
            const float Mx = fmax_x2(fmax_x1(fmaxf(Plo, Phi)));
            const int ex = ((__float_as_int(Mx) >> 23) & 255) - 127;
            const float s = __int_as_float((unsigned)(127 - ex) << 23);
            Plo *= s;
            Phi *= s;
            scale += ex;
        }
    }
    const float base = (float)scale * 0.6931471805599453f;
    float* gb = gbuf + ((long)(n * CHUNKS + ch)) * 64;
    gb[q * 8 + d] = __logf(Plo) + base;
    gb[q * 8 + 4 + d] = __logf(Phi) + base;
}

// ---------------- butterfly lse helpers for kC ----------------
__device__ inline float lse8(float v) {
    const float m = max8(v);
    return m + __logf(sum8(__expf(v - m)));
}
__device__ inline float lse64(float v) {
    float m = v;
#pragma unroll
    for (int d = 1; d < 64; d <<= 1) m = fmaxf(m, __shfl_xor(m, d));
    float e = __expf(v - m);
#pragma unroll
    for (int d = 1; d < 64; d <<= 1) e += __shfl_xor(e, d);
    return m + __logf(e);
}

// ---------------- Kernel C: fold chunk matrices, emit logZ/T -------------
__global__ __launch_bounds__(64) void kC_combine(const float* __restrict__ gbuf,
                                                 float* __restrict__ logZT) {
    const int n = blockIdx.x;
    const int l = threadIdx.x;
    const int gi = (l & 7) * 8 + (l >> 3);
    float g[CHUNKS];
#pragma unroll
    for (int c = 0; c < CHUNKS; ++c)
        g[c] = gbuf[((long)(n * CHUNKS + c)) * 64 + gi];
    float u = -logf(8.f);
#pragma unroll
    for (int c = 0; c < CHUNKS; ++c) {
        const float nu = lse8(g[c] + u);
        u = __shfl(nu, ((l & 7) << 3) | (l >> 3));
    }
    const float z = lse64(u);
    if (l == 0) logZT[n] = z / (float)TT;
}

// ---------------- Kernel D: bf16 scores -> final f32 output --------------
__global__ __launch_bounds__(128) void kD_final(const ushort* __restrict__ sc,
                                                const float* __restrict__ logZT,
                                                float* __restrict__ out) {
    __shared__ float dout[128 * SOUT];
    const int tid = threadIdx.x;
    const long row0 = (long)blockIdx.x * 128;
    const long row = row0 + tid;
    const int n = (int)(row & (NN - 1));
    const float z = logZT[n];
    const ushort* srow = sc + row * SOUT;
    float st[48];
#pragma unroll
    for (int i = 0; i < 6; ++i) {
        const uint4 qv = reinterpret_cast<const uint4*>(srow)[i];
        const unsigned wv[4] = {qv.x, qv.y, qv.z, qv.w};
#pragma unroll
        for (int t = 0; t < 4; ++t) {
            st[8 * i + 2 * t]     = __uint_as_float(wv[t] << 16);
            st[8 * i + 2 * t + 1] = __uint_as_float(wv[t] & 0xffff0000u);
        }
    }
    float* a = &dout[tid * SOUT];
#pragma unroll
    for (int c = 0; c < 40; ++c) a[c] = st[sidx(c)] - z;
    const float y40 = st[40], y41 = st[41], y42 = st[42], y43 = st[43], y44 = st[44];
    const float m3 = fmaxf(fmaxf(y40, y41), y42);
    const float l3 = m3 + __logf(__expf(y40 - m3) + __expf(y41 - m3) + __expf(y42 - m3));
    a[40] = y40 - l3; a[41] = y41 - l3; a[42] = y42 - l3;
    const float mA = fmaxf(y40, y43);
    const float lA = mA + __logf(__expf(y40 - mA) + __expf(y43 - mA));
    a[43] = y40 - lA; a[44] = y43 - lA;
    a[45] = 0.f;
    const float mB = fmaxf(y40, y44);
    const float lB = mB + __logf(__expf(y40 - mB) + __expf(y44 - mB));
    a[46] = y40 - lB; a[47] = y44 - lB;
    __syncthreads();
    const float4* sf = reinterpret_cast<const float4*>(dout);
    float4* df = reinterpret_cast<float4*>(out + row0 * SOUT);
#pragma unroll
    for (int kq = 0; kq < 12; ++kq)
        df[kq * 128 + tid] = sf[kq * 128 + tid];
}

extern "C" void kernel_launch(void* const* d_in, const int* in_sizes, int n_in,
                              void* d_out, int out_size, void* d_ws, size_t ws_size,
                              hipStream_t stream) {
    const float* x = (const float*)d_in[0];
    const float* W = (const float*)d_in[1];
    const float* b = (const float*)d_in[2];
    float* out = (float*)d_out;

    ushort* sc   = (ushort*)d_ws;                          // 49.15 MB
    float* gbuf  = (float*)((char*)d_ws + 49152000);       // 2.62 MB
    float* logZT = gbuf + (long)NN * CHUNKS * 64;          // 256 f32
    float* b48   = logZT + NN;                             // 48 f32
    ushort* Whi  = (ushort*)(b48 + SOUT);                  // 24 KB

    hipLaunchKernelGGL(kPrep, dim3(SOUT), dim3(DD), 0, stream, W, b, Whi, b48);
    hipLaunchKernelGGL(kA_mfma, dim3((TT * NN) / 128), dim3(512), 0, stream, x, Whi, b48, sc);
    hipLaunchKernelGGL(kB_scan, dim3(NN, CHUNKS / 8), dim3(256), 0, stream, sc, gbuf);
    hipLaunchKernelGGL(kC_combine, dim3(NN), dim3(64), 0, stream, gbuf, logZT);
    hipLaunchKernelGGL(kD_final, dim3((TT * NN) / 128), dim3(128), 0, stream, sc, logZT, out);
}

// Round 21
// 172.763 us; speedup vs baseline: 9.5000x; 1.0233x over previous
//
#include <hip/hip_runtime.h>
#include <hip/hip_bf16.h>
#include <math.h>

#define TT 2000
#define NN 256
#define DD 256
#define SS 45
#define SOUT 48
#define NTRANS_C 40
#define CHUNKS 40
#define CLEN 50   // TT / CHUNKS
#define BK 32     // x K-chunk (floats)
#define NCH (DD / BK)   // 8 chunks
#define XPAD 40   // bf16 x-tile row stride (ushorts)

typedef __attribute__((ext_vector_type(8))) short bf16x8;
typedef __attribute__((ext_vector_type(4))) float f32x4;

__device__ __forceinline__ int cvtpk(float lo, float hi) {
    int r;
    asm("v_cvt_pk_bf16_f32 %0, %1, %2" : "=v"(r) : "v"(lo), "v"(hi));
    return r;
}
__device__ inline ushort f2bf_rne(float f) {
    unsigned u = __float_as_uint(f);
    unsigned r = u + 0x7fffu + ((u >> 16) & 1u);
    return (ushort)(r >> 16);
}
__device__ __forceinline__ float bf2f(ushort h) {
    return __uint_as_float(((unsigned)h) << 16);
}
__device__ __host__ __forceinline__ constexpr int sidx(int c) {
    return (c < 32) ? (4 * (c & 7) + (c >> 3))
         : (c < 36) ? (32 + 2 * (c - 32))
         : (c < 40) ? (32 + 2 * (c - 36) + 1)
         : c;
}
__device__ __forceinline__ int swz_idx(int s, int koff) {
    return s * DD + ((((koff >> 3) ^ (s & 7)) << 3) | (koff & 7));
}

// ---------------- Kernel A: R20 structure + inline W-prep ----------------
// kPrep folded in: W (L2/L3-resident after first blocks) converted f32->bf16
// (cvtpk, RNE) during the per-block LDS W-stage; bias read from b directly.
__global__ __launch_bounds__(512, 6) void kA_mfma(const float* __restrict__ x,
                                                  const float* __restrict__ W,
                                                  const float* __restrict__ b,
                                                  ushort* __restrict__ sc) {
    __shared__ ushort Wl[SOUT * DD];
    __shared__ ushort xw[8][16 * XPAD];
    const int tid = threadIdx.x;
    // stage + convert W: 3 chunks of 8 cols per thread
    for (int idx = tid; idx < SOUT * (DD / 8); idx += 512) {
        const int s = idx >> 5;            // row 0..47
        const int c8 = (idx & 31) * 8;     // col (floats), multiple of 8
        float4 wa = {0.f, 0.f, 0.f, 0.f}, wb = {0.f, 0.f, 0.f, 0.f};
        if (s < SS) {
            wa = *reinterpret_cast<const float4*>(W + s * DD + c8);
            wb = *reinterpret_cast<const float4*>(W + s * DD + c8 + 4);
        }
        int4 pk;
        pk.x = cvtpk(wa.x, wa.y);
        pk.y = cvtpk(wa.z, wa.w);
        pk.z = cvtpk(wb.x, wb.y);
        pk.w = cvtpk(wb.z, wb.w);
        *reinterpret_cast<int4*>(&Wl[swz_idx(s, c8)]) = pk;
    }
    __syncthreads();

    const int l = tid & 63, w = tid >> 6;
    const long m0 = (long)blockIdx.x * 128;
    const int r16 = l & 15;
    const int kg = l >> 4;
    const int lrow = l >> 3;
    const int lcol = (l & 7) * 4;
    const float* xp = x + (m0 + w * 16 + lrow) * DD + lcol;
    const float* xq = xp + 8 * DD;
    ushort* xs = xw[w];
    int2* xw0 = reinterpret_cast<int2*>(&xs[lrow * XPAD + lcol]);
    int2* xw1 = reinterpret_cast<int2*>(&xs[(lrow + 8) * XPAD + lcol]);
    const bf16x8* xrd = reinterpret_cast<const bf16x8*>(&xs[r16 * XPAD + kg * 8]);

    f32x4 acc[3] = {{0, 0, 0, 0}, {0, 0, 0, 0}, {0, 0, 0, 0}};

    float4 pf[3][2];
#pragma unroll
    for (int v = 0; v < 3; ++v) {
        pf[v][0] = *reinterpret_cast<const float4*>(xp + v * BK);
        pf[v][1] = *reinterpret_cast<const float4*>(xq + v * BK);
    }

#pragma unroll
    for (int c = 0; c < NCH; ++c) {
        const float4 pa = pf[c % 3][0];
        const float4 qa = pf[c % 3][1];
        xw0->x = cvtpk(pa.x, pa.y);
        xw0->y = cvtpk(pa.z, pa.w);
        xw1->x = cvtpk(qa.x, qa.y);
        xw1->y = cvtpk(qa.z, qa.w);
        if (c + 3 < NCH) {
            pf[c % 3][0] = *reinterpret_cast<const float4*>(xp + (c + 3) * BK);
            pf[c % 3][1] = *reinterpret_cast<const float4*>(xq + (c + 3) * BK);
        }
        __builtin_amdgcn_sched_barrier(0);
        const bf16x8 a = *xrd;
        const int koff = c * BK + kg * 8;
        const bf16x8 b0 = *reinterpret_cast<const bf16x8*>(&Wl[swz_idx(0 * 16 + r16, koff)]);
        const bf16x8 b1 = *reinterpret_cast<const bf16x8*>(&Wl[swz_idx(1 * 16 + r16, koff)]);
        const bf16x8 b2 = *reinterpret_cast<const bf16x8*>(&Wl[swz_idx(2 * 16 + r16, koff)]);
        acc[0] = __builtin_amdgcn_mfma_f32_16x16x32_bf16(a, b0, acc[0], 0, 0, 0);
        acc[1] = __builtin_amdgcn_mfma_f32_16x16x32_bf16(a, b1, acc[1], 0, 0, 0);
        acc[2] = __builtin_amdgcn_mfma_f32_16x16x32_bf16(a, b2, acc[2], 0, 0, 0);
    }

    __syncthreads();
    ushort* se = Wl;
#pragma unroll
    for (int jt = 0; jt < 3; ++jt) {
        const int col = jt * 16 + r16;
        const float bias = (col < SS) ? b[col] : 0.f;
        int si;
        if (jt < 2) si = 4 * (col & 7) + (col >> 3);
        else if (r16 < 8) si = (r16 < 4) ? (32 + 2 * r16) : (32 + 2 * (r16 - 4) + 1);
        else si = 40 + (r16 - 8);
#pragma unroll
        for (int r = 0; r < 4; ++r) {
            const int lr = w * 16 + kg * 4 + r;
            const float y = acc[jt][r] + bias;
            float v;
            if (col < NTRANS_C) {
                const float e = __expf(2.f * y);
                v = 5.f * (1.f - 2.f / (e + 1.f));
            } else {
                v = y;
            }
            se[lr * SOUT + si] = f2bf_rne(v);
        }
    }
    __syncthreads();
    const uint4* su = reinterpret_cast<const uint4*>(se);
    uint4* du = reinterpret_cast<uint4*>(sc + m0 * SOUT);
    du[tid] = su[tid];
    if (tid < 256) du[512 + tid] = su[512 + tid];
}

// ---------------- DPP / swizzle cross-lane helpers -----------------------
#define DPP_XOR1 0xB1
#define DPP_XOR2 0x4E

__device__ inline float fmax_x1(float v) {
    const int d = __builtin_amdgcn_mov_dpp(__float_as_int(v), DPP_XOR1, 0xF, 0xF, true);
    return fmaxf(v, __int_as_float(d));
}
__device__ inline float fmax_x2(float v) {
    const int d = __builtin_amdgcn_mov_dpp(__float_as_int(v), DPP_XOR2, 0xF, 0xF, true);
    return fmaxf(v, __int_as_float(d));
}
__device__ inline float add_x1(float v) {
    const int d = __builtin_amdgcn_mov_dpp(__float_as_int(v), DPP_XOR1, 0xF, 0xF, true);
    return v + __int_as_float(d);
}
__device__ inline float add_x2(float v) {
    const int d = __builtin_amdgcn_mov_dpp(__float_as_int(v), DPP_XOR2, 0xF, 0xF, true);
    return v + __int_as_float(d);
}
__device__ inline float swz4(float v) {   // lane ^ 4
    return __int_as_float(__builtin_amdgcn_ds_swizzle(__float_as_int(v), 0x101F));
}
__device__ inline float fmax_x4(float v) { return fmaxf(v, swz4(v)); }
__device__ inline float add_x4(float v) { return v + swz4(v); }
__device__ inline float sum8(float v) { return add_x4(add_x2(add_x1(v))); }
__device__ inline float max8(float v) { return fmax_x4(fmax_x2(fmax_x1(v))); }

// ---------------- Kernel B: pair-layout scan, 4-slot score queue ---------
// Queue depth 3->4: load-to-use distance = 3 iterations (~550+ cyc), fully
// covering L3 latency. Indices compile-time under the full unroll.
__global__ __launch_bounds__(256) void kB_scan(const ushort* __restrict__ sc,
                                               float* __restrict__ gbuf) {
    __shared__ float elp[8][2][48][2];   // 24.6 KB: [half][buf][slot][par]
    const int n = blockIdx.x;
    const int tid = threadIdx.x;
    const int h = tid >> 5;          // 0..7 -> chunk within block
    const int l32 = tid & 31;
    const int d = l32 & 3;           // state index within quad
    const int q = l32 >> 2;          // column 0..7
    const int ch = blockIdx.y * 8 + h;
    const long stride = (long)NN * SOUT;
    const ushort* sp = sc + ((long)(ch * CLEN) * NN + n) * SOUT;   // row t=0

    float Plo = (d == q) ? 1.f : 0.f;        // M[d][col]
    float Phi = (4 + d == q) ? 1.f : 0.f;    // M[4+d][col]
    int scale = 0;

    // stage E for t=0,1 into u-parity buffer 0
    {
        float2 e2 = { __expf(bf2f(sp[l32])), __expf(bf2f(sp[stride + l32])) };
        *reinterpret_cast<float2*>(&elp[h][0][l32][0]) = e2;
        if (l32 < 8) {
            float2 f2 = { __expf(bf2f(sp[32 + l32])),
                          __expf(bf2f(sp[stride + 32 + l32])) };
            *reinterpret_cast<float2*>(&elp[h][0][32 + l32][0]) = f2;
        }
    }

    // register score-queue (depth 4): slot v%4 holds raw scores of steps 2v+2, 2v+3
    ushort qa[4], qb[4], qc[4], qd[4];
#pragma unroll
    for (int v = 0; v < 3; ++v) {   // prologue: fill v=0,1,2
        const ushort* rA_ = sp + (long)(2 * v + 2) * stride;
        const ushort* rB_ = sp + (long)(2 * v + 3) * stride;
        qa[v] = rA_[l32];
        qb[v] = rB_[l32];
        if (l32 < 8) { qc[v] = rA_[32 + l32]; qd[v] = rB_[32 + l32]; }
    }

#pragma unroll
    for (int u = 0; u < CLEN / 2; ++u) {
        // E-write for steps 2u+2, 2u+3 from queue slot u%4 (loaded 3 iters ago)
        if (u <= CLEN / 2 - 2) {
            float2 e2 = { __expf(bf2f(qa[u % 4])), __expf(bf2f(qb[u % 4])) };
            *reinterpret_cast<float2*>(&elp[h][(u + 1) & 1][l32][0]) = e2;
            if (l32 < 8) {
                float2 f2 = { __expf(bf2f(qc[u % 4])), __expf(bf2f(qd[u % 4])) };
                *reinterpret_cast<float2*>(&elp[h][(u + 1) & 1][32 + l32][0]) = f2;
            }
        }
        // refill slot (u+3)%4 with scores of steps 2u+8, 2u+9 (used at u+3)
        if (u + 3 <= CLEN / 2 - 2) {
            const ushort* rA_ = sp + (long)(2 * u + 8) * stride;
            const ushort* rB_ = sp + (long)(2 * u + 9) * stride;
            qa[(u + 3) % 4] = rA_[l32];
            qb[(u + 3) % 4] = rB_[l32];
            if (l32 < 8) { qc[(u + 3) % 4] = rA_[32 + l32]; qd[(u + 3) % 4] = rB_[32 + l32]; }
        }
        // 5 vector reads serve BOTH steps
        const float* eb = &elp[h][u & 1][0][0];
        const float4 rA = *reinterpret_cast<const float4*>(eb + (4 * d) * 2);
        const float4 rB = *reinterpret_cast<const float4*>(eb + (4 * d + 2) * 2);
        const float4 rC = *reinterpret_cast<const float4*>(eb + (16 + 4 * d) * 2);
        const float4 rD = *reinterpret_cast<const float4*>(eb + (16 + 4 * d + 2) * 2);
        const float4 rE = *reinterpret_cast<const float4*>(eb + (32 + 2 * d) * 2);

        // ---- step t = 2u (parity 0): components .x/.z ----
        {
            float v0 = fmaf(Plo, rA.x, Phi * rC.x);
            float v1 = fmaf(Plo, rA.z, Phi * rC.z);
            float v2 = fmaf(Plo, rB.x, Phi * rD.x);
            float v3 = fmaf(Plo, rB.z, Phi * rD.z);
            v0 = add_x2(add_x1(v0));
            v1 = add_x2(add_x1(v1));
            v2 = add_x2(add_x1(v2));
            v3 = add_x2(add_x1(v3));
            const float PhiN = fmaf(Plo, rE.x, Phi * rE.z);
            const float pa_ = (d & 1) ? v1 : v0;
            const float pb_ = (d & 1) ? v3 : v2;
            Plo = (d & 2) ? pb_ : pa_;
            Phi = PhiN;
        }
        // ---- step t = 2u+1 (parity 1): components .y/.w ----
        {
            float v0 = fmaf(Plo, rA.y, Phi * rC.y);
            float v1 = fmaf(Plo, rA.w, Phi * rC.w);
            float v2 = fmaf(Plo, rB.y, Phi * rD.y);
            float v3 = fmaf(Plo, rB.w, Phi * rD.w);
            v0 = add_x2(add_x1(v0));
            v1 = add_x2(add_x1(v1));
            v2 = add_x2(add_x1(v2));
            v3 = add_x2(add_x1(v3));
            const float PhiN = fmaf(Plo, rE.y, Phi * rE.w);
            const float pa_ = (d & 1) ? v1 : v0;
            const float pb_ = (d & 1) ? v3 : v2;
            Plo = (d & 2) ? pb_ : pa_;
            Phi = PhiN;
        }
        if (u & 1) {   // t = 4k+3: exact pow2 rescale, per-quad
            const float Mx = fmax_x2(fmax_x1(fmaxf(Plo, Phi)));
            const int ex = ((__float_as_int(Mx) >> 23) & 255) - 127;
            const float s = __int_as_float((unsigned)(127 - ex) << 23);
            Plo *= s;
            Phi *= s;
            scale += ex;
        }
    }
    const float base = (float)scale * 0.6931471805599453f;
    float* gb = gbuf + ((long)(n * CHUNKS + ch)) * 64;
    gb[q * 8 + d] = __logf(Plo) + base;
    gb[q * 8 + 4 + d] = __logf(Phi) + base;
}

// ---------------- butterfly lse helpers for kC ----------------
__device__ inline float lse8(float v) {
    const float m = max8(v);
    return m + __logf(sum8(__expf(v - m)));
}
__device__ inline float lse64(float v) {
    float m = v;
#pragma unroll
    for (int d = 1; d < 64; d <<= 1) m = fmaxf(m, __shfl_xor(m, d));
    float e = __expf(v - m);
#pragma unroll
    for (int d = 1; d < 64; d <<= 1) e += __shfl_xor(e, d);
    return m + __logf(e);
}

// ---------------- Kernel C: fold chunk matrices, emit logZ/T -------------
__global__ __launch_bounds__(64) void kC_combine(const float* __restrict__ gbuf,
                                                 float* __restrict__ logZT) {
    const int n = blockIdx.x;
    const int l = threadIdx.x;
    const int gi = (l & 7) * 8 + (l >> 3);
    float g[CHUNKS];
#pragma unroll
    for (int c = 0; c < CHUNKS; ++c)
        g[c] = gbuf[((long)(n * CHUNKS + c)) * 64 + gi];
    float u = -logf(8.f);
#pragma unroll
    for (int c = 0; c < CHUNKS; ++c) {
        const float nu = lse8(g[c] + u);
        u = __shfl(nu, ((l & 7) << 3) | (l >> 3));
    }
    const float z = lse64(u);
    if (l == 0) logZT[n] = z / (float)TT;
}

// ---------------- Kernel D: bf16 scores -> final f32 output --------------
__global__ __launch_bounds__(128) void kD_final(const ushort* __restrict__ sc,
                                                const float* __restrict__ logZT,
                                                float* __restrict__ out) {
    __shared__ float dout[128 * SOUT];
    const int tid = threadIdx.x;
    const long row0 = (long)blockIdx.x * 128;
    const long row = row0 + tid;
    const int n = (int)(row & (NN - 1));
    const float z = logZT[n];
    const ushort* srow = sc + row * SOUT;
    float st[48];
#pragma unroll
    for (int i = 0; i < 6; ++i) {
        const uint4 qv = reinterpret_cast<const uint4*>(srow)[i];
        const unsigned wv[4] = {qv.x, qv.y, qv.z, qv.w};
#pragma unroll
        for (int t = 0; t < 4; ++t) {
            st[8 * i + 2 * t]     = __uint_as_float(wv[t] << 16);
            st[8 * i + 2 * t + 1] = __uint_as_float(wv[t] & 0xffff0000u);
        }
    }
    float* a = &dout[tid * SOUT];
#pragma unroll
    for (int c = 0; c < 40; ++c) a[c] = st[sidx(c)] - z;
    const float y40 = st[40], y41 = st[41], y42 = st[42], y43 = st[43], y44 = st[44];
    const float m3 = fmaxf(fmaxf(y40, y41), y42);
    const float l3 = m3 + __logf(__expf(y40 - m3) + __expf(y41 - m3) + __expf(y42 - m3));
    a[40] = y40 - l3; a[41] = y41 - l3; a[42] = y42 - l3;
    const float mA = fmaxf(y40, y43);
    const float lA = mA + __logf(__expf(y40 - mA) + __expf(y43 - mA));
    a[43] = y40 - lA; a[44] = y43 - lA;
    a[45] = 0.f;
    const float mB = fmaxf(y40, y44);
    const float lB = mB + __logf(__expf(y40 - mB) + __expf(y44 - mB));
    a[46] = y40 - lB; a[47] = y44 - lB;
    __syncthreads();
    const float4* sf = reinterpret_cast<const float4*>(dout);
    float4* df = reinterpret_cast<float4*>(out + row0 * SOUT);
#pragma unroll
    for (int kq = 0; kq < 12; ++kq)
        df[kq * 128 + tid] = sf[kq * 128 + tid];
}

extern "C" void kernel_launch(void* const* d_in, const int* in_sizes, int n_in,
                              void* d_out, int out_size, void* d_ws, size_t ws_size,
                              hipStream_t stream) {
    const float* x = (const float*)d_in[0];
    const float* W = (const float*)d_in[1];
    const float* b = (const float*)d_in[2];
    float* out = (float*)d_out;

    ushort* sc   = (ushort*)d_ws;                          // 49.15 MB
    float* gbuf  = (float*)((char*)d_ws + 49152000);       // 2.62 MB
    float* logZT = gbuf + (long)NN * CHUNKS * 64;          // 256 f32

    hipLaunchKernelGGL(kA_mfma, dim3((TT * NN) / 128), dim3(512), 0, stream, x, W, b, sc);
    hipLaunchKernelGGL(kB_scan, dim3(NN, CHUNKS / 8), dim3(256), 0, stream, sc, gbuf);
    hipLaunchKernelGGL(kC_combine, dim3(NN), dim3(64), 0, stream, gbuf, logZT);
    hipLaunchKernelGGL(kD_final, dim3((TT * NN) / 128), dim3(128), 0, stream, sc, logZT, out);
}